// Round 1
// baseline (4157.406 us; speedup 1.0000x reference)
//
#include <hip/hip_runtime.h>
#include <cmath>

#define Bsz 64
#define Tt  512
#define Dd  768
#define Wn  255
#define Hh  8
#define DHd 96
#define NROWS (Bsz*Wn)   // 16320

// ---------------- gather: first-subtoken index + feature copy ----------------

__global__ void k_init_fi(int* fi) {
    int i = blockIdx.x * 256 + threadIdx.x;
    if (i < Bsz * Wn) fi[i] = 0x7fffffff;
}

__global__ void k_scan(const int* __restrict__ wid, int* __restrict__ fi) {
    int i = blockIdx.x * 256 + threadIdx.x;   // over B*T
    if (i >= Bsz * Tt) return;
    int b = i / Tt, t = i % Tt;
    int w = wid[i];
    if (w >= 0 && w < Wn) atomicMin(&fi[b * Wn + w], t);
}

__global__ void k_gather(const float4* __restrict__ ob, const int* __restrict__ fi,
                         float4* __restrict__ feat) {
    int i = blockIdx.x * 256 + threadIdx.x;   // over NROWS*192
    if (i >= NROWS * 192) return;
    int r = i / 192, c = i % 192;
    int b = r / Wn;
    int idx = fi[r];
    if (idx == 0x7fffffff) idx = 0;           // argmax(all-False) == 0
    feat[i] = ob[((size_t)b * Tt + idx) * 192 + c];
}

// ---------------- generic fp32 GEMM: C = A@W + bias (+res) (+relu) ----------
// A: [M,K] row-major, W: [K,N] row-major. 128x128 block tile, 8x8 micro-tile.

template<int RELU>
__global__ __launch_bounds__(256) void k_gemm(const float* __restrict__ A,
                                              const float* __restrict__ Wt,
                                              const float* __restrict__ bias,
                                              const float* __restrict__ res,
                                              float* __restrict__ C,
                                              int M, int N, int K) {
    __shared__ float As[16][132];
    __shared__ float Bs[16][128];
    const int tid = threadIdx.x;
    const int bn = blockIdx.x, bm = blockIdx.y;
    const int tx = tid & 15, ty = tid >> 4;
    const int row0 = bm * 128, col0 = bn * 128;
    float acc[8][8] = {};

    for (int k0 = 0; k0 < K; k0 += 16) {
        #pragma unroll
        for (int j = 0; j < 2; ++j) {
            int idx = tid + j * 256;
            int m = idx >> 2, kk = (idx & 3) * 4;
            int row = row0 + m; if (row >= M) row = M - 1;
            const float4 av = *(const float4*)(A + (size_t)row * K + k0 + kk);
            As[kk + 0][m] = av.x; As[kk + 1][m] = av.y;
            As[kk + 2][m] = av.z; As[kk + 3][m] = av.w;
        }
        #pragma unroll
        for (int j = 0; j < 2; ++j) {
            int idx = tid + j * 256;
            int kk = idx >> 5, n4 = (idx & 31) * 4;
            const float4 bv = *(const float4*)(Wt + (size_t)(k0 + kk) * N + col0 + n4);
            *(float4*)&Bs[kk][n4] = bv;
        }
        __syncthreads();
        #pragma unroll
        for (int kk = 0; kk < 16; ++kk) {
            float a[8], bb[8];
            #pragma unroll
            for (int i = 0; i < 8; ++i) a[i] = As[kk][ty * 8 + i];
            #pragma unroll
            for (int i = 0; i < 8; ++i) bb[i] = Bs[kk][tx * 8 + i];
            #pragma unroll
            for (int i = 0; i < 8; ++i)
                #pragma unroll
                for (int j = 0; j < 8; ++j) acc[i][j] += a[i] * bb[j];
        }
        __syncthreads();
    }
    #pragma unroll
    for (int i = 0; i < 8; ++i) {
        int row = row0 + ty * 8 + i;
        if (row >= M) break;
        #pragma unroll
        for (int j = 0; j < 8; j += 4) {
            int col = col0 + tx * 8 + j;
            float4 o;
            o.x = acc[i][j + 0] + bias[col + 0];
            o.y = acc[i][j + 1] + bias[col + 1];
            o.z = acc[i][j + 2] + bias[col + 2];
            o.w = acc[i][j + 3] + bias[col + 3];
            if (res) {
                const float4 rv = *(const float4*)(res + (size_t)row * N + col);
                o.x += rv.x; o.y += rv.y; o.z += rv.z; o.w += rv.w;
            }
            if (RELU) {
                o.x = fmaxf(o.x, 0.f); o.y = fmaxf(o.y, 0.f);
                o.z = fmaxf(o.z, 0.f); o.w = fmaxf(o.w, 0.f);
            }
            *(float4*)(C + (size_t)row * N + col) = o;
        }
    }
}

// ---------------- fused attention per (b,h); ctx written in-place over q ----
// Safe aliasing: each (b,h) block owns disjoint columns h*96..h*96+95, and a
// q row is written only after it has been staged to LDS for its own tile.

__global__ __launch_bounds__(256) void k_attn(const float* q, const float* __restrict__ kmat,
                                              const float* __restrict__ v, float* ctx) {
    const int b = blockIdx.x >> 3, h = blockIdx.x & 7;
    const int tid = threadIdx.x;
    __shared__ float qv[8][96];
    __shared__ float pL[8][256];
    __shared__ float mrow[8], drow[8];
    __shared__ float4 part[10][8][24];
    const float scale = 0.10206207261596575f;  // 1/sqrt(96)
    const size_t rowbase = (size_t)b * Wn;

    for (int q0 = 0; q0 < Wn; q0 += 8) {
        const int qn = min(8, Wn - q0);
        for (int idx = tid; idx < 8 * 96; idx += 256) {
            int qj = idx / 96, d = idx % 96;
            int row = q0 + qj; if (row > Wn - 1) row = Wn - 1;
            qv[qj][d] = q[(rowbase + row) * Dd + h * DHd + d];
        }
        __syncthreads();
        // scores: thread t handles key t
        if (tid < Wn) {
            const float4* kp = (const float4*)(kmat + (rowbase + tid) * Dd + h * DHd);
            float s[8] = {0, 0, 0, 0, 0, 0, 0, 0};
            #pragma unroll 4
            for (int d4 = 0; d4 < 24; ++d4) {
                float4 kv = kp[d4];
                #pragma unroll
                for (int qj = 0; qj < 8; ++qj) {
                    s[qj] += kv.x * qv[qj][d4 * 4 + 0] + kv.y * qv[qj][d4 * 4 + 1]
                           + kv.z * qv[qj][d4 * 4 + 2] + kv.w * qv[qj][d4 * 4 + 3];
                }
            }
            #pragma unroll
            for (int qj = 0; qj < 8; ++qj) pL[qj][tid] = s[qj] * scale;
        } else {
            #pragma unroll
            for (int qj = 0; qj < 8; ++qj) pL[qj][255] = -3.0e38f;
        }
        __syncthreads();
        {   // row max, 32-lane group per q-row
            int qj = tid >> 5, lane = tid & 31;
            float m = -3.0e38f;
            for (int t = lane; t < Wn; t += 32) m = fmaxf(m, pL[qj][t]);
            #pragma unroll
            for (int off = 16; off > 0; off >>= 1) m = fmaxf(m, __shfl_xor(m, off, 32));
            if (lane == 0) mrow[qj] = m;
        }
        __syncthreads();
        #pragma unroll
        for (int qj = 0; qj < 8; ++qj) {
            if (tid < Wn) pL[qj][tid] = __expf(pL[qj][tid] - mrow[qj]);
            else          pL[qj][255] = 0.0f;
        }
        __syncthreads();
        {   // row sum
            int qj = tid >> 5, lane = tid & 31;
            float ssum = 0.0f;
            for (int t = lane; t < Wn; t += 32) ssum += pL[qj][t];
            #pragma unroll
            for (int off = 16; off > 0; off >>= 1) ssum += __shfl_xor(ssum, off, 32);
            if (lane == 0) drow[qj] = ssum;
        }
        __syncthreads();
        // ctx partials: 10 key-groups x 24 float4 lanes
        if (tid < 240) {
            int g = tid / 24, d4 = tid % 24;
            float4 acc[8];
            #pragma unroll
            for (int qj = 0; qj < 8; ++qj) { acc[qj].x = 0; acc[qj].y = 0; acc[qj].z = 0; acc[qj].w = 0; }
            for (int t = g; t < Wn; t += 10) {
                const float4* vp = (const float4*)(v + (rowbase + t) * Dd + h * DHd);
                float4 vv = vp[d4];
                #pragma unroll
                for (int qj = 0; qj < 8; ++qj) {
                    float p = pL[qj][t];
                    acc[qj].x += p * vv.x; acc[qj].y += p * vv.y;
                    acc[qj].z += p * vv.z; acc[qj].w += p * vv.w;
                }
            }
            #pragma unroll
            for (int qj = 0; qj < 8; ++qj) part[g][qj][d4] = acc[qj];
        }
        __syncthreads();
        if (tid < 192) {
            int qj = tid / 24, d4 = tid % 24;
            if (qj < qn) {
                float4 s = {0, 0, 0, 0};
                #pragma unroll
                for (int g = 0; g < 10; ++g) {
                    float4 p = part[g][qj][d4];
                    s.x += p.x; s.y += p.y; s.z += p.z; s.w += p.w;
                }
                float inv = 1.0f / drow[qj];
                s.x *= inv; s.y *= inv; s.z *= inv; s.w *= inv;
                *(float4*)(ctx + (rowbase + q0 + qj) * Dd + h * DHd + d4 * 4) = s;
            }
        }
        __syncthreads();
    }
}

// ---------------- row LayerNorm: Y = (x-m)/sqrt(v+eps)*g + b ----------------

__global__ __launch_bounds__(256) void k_ln(const float* __restrict__ X, const float* __restrict__ g,
                                            const float* __restrict__ bt, float* __restrict__ Y) {
    const int r = blockIdx.x, tid = threadIdx.x;
    __shared__ float red[256];
    const float* x = X + (size_t)r * Dd;
    float x0 = x[tid], x1 = x[tid + 256], x2 = x[tid + 512];
    red[tid] = x0 + x1 + x2; __syncthreads();
    for (int s = 128; s > 0; s >>= 1) { if (tid < s) red[tid] += red[tid + s]; __syncthreads(); }
    float mean = red[0] * (1.0f / 768.0f);
    __syncthreads();
    float d0 = x0 - mean, d1 = x1 - mean, d2 = x2 - mean;
    red[tid] = d0 * d0 + d1 * d1 + d2 * d2; __syncthreads();
    for (int s = 128; s > 0; s >>= 1) { if (tid < s) red[tid] += red[tid + s]; __syncthreads(); }
    float rs = rsqrtf(red[0] * (1.0f / 768.0f) + 1e-5f);
    float* y = Y + (size_t)r * Dd;
    y[tid]       = d0 * rs * g[tid]       + bt[tid];
    y[tid + 256] = d1 * rs * g[tid + 256] + bt[tid + 256];
    y[tid + 512] = d2 * rs * g[tid + 512] + bt[tid + 512];
}

// ---------------- final LN + 2-class linear + softmax + argmax --------------

__global__ __launch_bounds__(256) void k_final(const float* __restrict__ X, const float* __restrict__ g,
                                               const float* __restrict__ bt, const float* __restrict__ lw,
                                               const float* __restrict__ lb, float* __restrict__ out) {
    const int r = blockIdx.x, tid = threadIdx.x;
    __shared__ float red[256];
    const float* x = X + (size_t)r * Dd;
    float x0 = x[tid], x1 = x[tid + 256], x2 = x[tid + 512];
    red[tid] = x0 + x1 + x2; __syncthreads();
    for (int s = 128; s > 0; s >>= 1) { if (tid < s) red[tid] += red[tid + s]; __syncthreads(); }
    float mean = red[0] * (1.0f / 768.0f);
    __syncthreads();
    float d0 = x0 - mean, d1 = x1 - mean, d2 = x2 - mean;
    red[tid] = d0 * d0 + d1 * d1 + d2 * d2; __syncthreads();
    for (int s = 128; s > 0; s >>= 1) { if (tid < s) red[tid] += red[tid + s]; __syncthreads(); }
    float rs = rsqrtf(red[0] * (1.0f / 768.0f) + 1e-5f);
    __syncthreads();
    float n0 = d0 * rs * g[tid]       + bt[tid];
    float n1 = d1 * rs * g[tid + 256] + bt[tid + 256];
    float n2 = d2 * rs * g[tid + 512] + bt[tid + 512];
    float l0 = n0 * lw[2 * tid]     + n1 * lw[2 * (tid + 256)]     + n2 * lw[2 * (tid + 512)];
    float l1 = n0 * lw[2 * tid + 1] + n1 * lw[2 * (tid + 256) + 1] + n2 * lw[2 * (tid + 512) + 1];
    red[tid] = l0; __syncthreads();
    for (int s = 128; s > 0; s >>= 1) { if (tid < s) red[tid] += red[tid + s]; __syncthreads(); }
    l0 = red[0]; __syncthreads();
    red[tid] = l1; __syncthreads();
    for (int s = 128; s > 0; s >>= 1) { if (tid < s) red[tid] += red[tid + s]; __syncthreads(); }
    l1 = red[0];
    if (tid == 0) {
        l0 += lb[0]; l1 += lb[1];
        float m = fmaxf(l0, l1);
        float e0 = expf(l0 - m), e1 = expf(l1 - m);
        float inv = 1.0f / (e0 + e1);
        out[2 * r] = e0 * inv;
        out[2 * r + 1] = e1 * inv;
        out[2 * NROWS + r] = (l1 > l0) ? 1.0f : 0.0f;   // tie -> first index (0)
    }
}

// ---------------- launch --------------------------------------------------

extern "C" void kernel_launch(void* const* d_in, const int* in_sizes, int n_in,
                              void* d_out, int out_size, void* d_ws, size_t ws_size,
                              hipStream_t stream) {
    const float* ob  = (const float*)d_in[0];
    const int*   wid = (const int*)d_in[1];
    const float* Wq  = (const float*)d_in[2];  const float* bq  = (const float*)d_in[3];
    const float* Wk  = (const float*)d_in[4];  const float* bk  = (const float*)d_in[5];
    const float* Wv  = (const float*)d_in[6];  const float* bv  = (const float*)d_in[7];
    const float* Wo  = (const float*)d_in[8];  const float* bo  = (const float*)d_in[9];
    const float* g1  = (const float*)d_in[10]; const float* b1  = (const float*)d_in[11];
    const float* W1f = (const float*)d_in[12]; const float* b1f = (const float*)d_in[13];
    const float* W2f = (const float*)d_in[14]; const float* b2f = (const float*)d_in[15];
    const float* g2  = (const float*)d_in[16]; const float* b2  = (const float*)d_in[17];
    const float* ng  = (const float*)d_in[18]; const float* nb  = (const float*)d_in[19];
    const float* lw  = (const float*)d_in[20]; const float* lb  = (const float*)d_in[21];
    float* out = (float*)d_out;

    char* ws = (char*)d_ws;
    const size_t MB = 1u << 20;
    const size_t SLOT = 50 * MB;               // 52,428,800 B >= 16320*768*4 and 4096*3072*4
    int*   fi    = (int*)ws;                   // 65,280 B
    float* featB = (float*)(ws + MB);          // A: feat, later x2
    float* qB    = (float*)(ws + MB + SLOT);   // B: q -> ctx (in-place) -> ff1 chunk buf
    float* kB    = (float*)(ws + MB + 2*SLOT); // C: k -> t1 -> t2
    float* vB    = (float*)(ws + MB + 3*SLOT); // D: v -> x

    k_init_fi<<<(Bsz * Wn + 255) / 256, 256, 0, stream>>>(fi);
    k_scan<<<(Bsz * Tt) / 256, 256, 0, stream>>>(wid, fi);
    k_gather<<<(NROWS * 192 + 255) / 256, 256, 0, stream>>>((const float4*)ob, fi, (float4*)featB);

    dim3 gqkv(Dd / 128, (NROWS + 127) / 128);
    k_gemm<0><<<gqkv, 256, 0, stream>>>(featB, Wq, bq, nullptr, qB, NROWS, Dd, Dd);
    k_gemm<0><<<gqkv, 256, 0, stream>>>(featB, Wk, bk, nullptr, kB, NROWS, Dd, Dd);
    k_gemm<0><<<gqkv, 256, 0, stream>>>(featB, Wv, bv, nullptr, vB, NROWS, Dd, Dd);

    k_attn<<<Bsz * Hh, 256, 0, stream>>>(qB, kB, vB, qB);   // ctx overwrites q

    // t1 = feat + ctx@Wo + bo  -> kB ; x = LN1(t1) -> vB
    k_gemm<0><<<gqkv, 256, 0, stream>>>(qB, Wo, bo, featB, kB, NROWS, Dd, Dd);
    k_ln<<<NROWS, 256, 0, stream>>>(kB, g1, b1, vB);

    // FFN in 4 row-chunks; hidden activation reuses qB (50 MiB)
    const int starts[4] = {0, 4096, 8192, 12288};
    const int sizes[4]  = {4096, 4096, 4096, 4032};
    for (int c = 0; c < 4; ++c) {
        const int r0 = starts[c], mc = sizes[c];
        dim3 gf1(3072 / 128, (mc + 127) / 128);
        k_gemm<1><<<gf1, 256, 0, stream>>>(vB + (size_t)r0 * Dd, W1f, b1f, nullptr, qB, mc, 3072, Dd);
        dim3 gf2(Dd / 128, (mc + 127) / 128);
        k_gemm<0><<<gf2, 256, 0, stream>>>(qB, W2f, b2f, vB + (size_t)r0 * Dd,
                                           kB + (size_t)r0 * Dd, mc, Dd, 3072);
    }
    // x2 = LN2(t2) -> featB ; final LN+linear+softmax+argmax -> out
    k_ln<<<NROWS, 256, 0, stream>>>(kB, g2, b2, featB);
    k_final<<<NROWS, 256, 0, stream>>>(featB, ng, nb, lw, lb, out);
}

// Round 4
// 1806.537 us; speedup vs baseline: 2.3013x; 2.3013x over previous
//
#include <hip/hip_runtime.h>
#include <cmath>

#define Bsz 64
#define Tt  512
#define Dd  768
#define Wn  255
#define Hh  8
#define DHd 96
#define NROWS (Bsz*Wn)   // 16320

typedef _Float16 half_t;
typedef _Float16 f16x8 __attribute__((ext_vector_type(8)));
typedef _Float16 f16x4 __attribute__((ext_vector_type(4)));
typedef float f32x4 __attribute__((ext_vector_type(4)));

// ---- split-fp16 weights (transposed [N][K]), ~27 MiB static device memory ----
// scales: weights x64, activations x16, GEMM epilogue descales by 1/1024.
#define OFF_WQ_H 0
#define OFF_WQ_L 589824
#define OFF_WK_H 1179648
#define OFF_WK_L 1769472
#define OFF_WV_H 2359296
#define OFF_WV_L 2949120
#define OFF_WO_H 3538944
#define OFF_WO_L 4128768
#define OFF_W1_H 4718592
#define OFF_W1_L 7077888
#define OFF_W2_H 9437184
#define OFF_W2_L 11796480
__device__ __align__(16) half_t g_w16[14155776];

__device__ __forceinline__ void gload16(const half_t* g, half_t* l) {
    __builtin_amdgcn_global_load_lds((const __attribute__((address_space(1))) void*)g,
                                     (__attribute__((address_space(3))) void*)l, 16, 0, 0);
}

// ---------------- gather: first-subtoken index + feature copy ----------------

__global__ void k_init_fi(int* fi) {
    int i = blockIdx.x * 256 + threadIdx.x;
    if (i < Bsz * Wn) fi[i] = 0x7fffffff;
}

__global__ void k_scan(const int* __restrict__ wid, int* __restrict__ fi) {
    int i = blockIdx.x * 256 + threadIdx.x;   // over B*T
    if (i >= Bsz * Tt) return;
    int b = i / Tt, t = i % Tt;
    int w = wid[i];
    if (w >= 0 && w < Wn) atomicMin(&fi[b * Wn + w], t);
}

// gather directly into interleaved fp16 hi/lo records (row = 1536 halves: hi[768]|lo[768])
__global__ void k_gather(const float4* __restrict__ ob, const int* __restrict__ fi,
                         half_t* __restrict__ f16) {
    int i = blockIdx.x * 256 + threadIdx.x;   // over NROWS*192
    if (i >= NROWS * 192) return;
    int r = i / 192, c = i % 192;
    int b = r / Wn;
    int idx = fi[r];
    if (idx == 0x7fffffff) idx = 0;           // argmax(all-False) == 0
    float4 v = ob[((size_t)b * Tt + idx) * 192 + c];
    float a0 = v.x * 16.f, a1 = v.y * 16.f, a2 = v.z * 16.f, a3 = v.w * 16.f;
    half_t h0 = (half_t)a0, h1 = (half_t)a1, h2 = (half_t)a2, h3 = (half_t)a3;
    f16x4 hv = {h0, h1, h2, h3};
    f16x4 lv = {(half_t)(a0 - (float)h0), (half_t)(a1 - (float)h1),
                (half_t)(a2 - (float)h2), (half_t)(a3 - (float)h3)};
    size_t off = (size_t)r * 1536 + c * 4;
    *(f16x4*)&f16[off] = hv;
    *(f16x4*)&f16[off + 768] = lv;
}

// ---------------- weight transpose + split: W[K,N] -> WT_h/WT_l [N,K] x64 ----

__global__ void k_wsplit(const float* __restrict__ Wm, int K, int N,
                         size_t off_h, size_t off_l) {
    __shared__ float sm[32][33];
    const int tx = threadIdx.x, ty = threadIdx.y;
    const int n0 = blockIdx.x * 32, k0 = blockIdx.y * 32;
    #pragma unroll
    for (int r = 0; r < 4; ++r)
        sm[ty + r * 8][tx] = Wm[(size_t)(k0 + ty + r * 8) * N + n0 + tx];
    __syncthreads();
    half_t* oh = g_w16 + off_h;
    half_t* ol = g_w16 + off_l;
    #pragma unroll
    for (int r = 0; r < 4; ++r) {
        float v = 64.f * sm[tx][ty + r * 8];
        half_t hi = (half_t)v;
        size_t o = (size_t)(n0 + ty + r * 8) * K + k0 + tx;
        oh[o] = hi;
        ol[o] = (half_t)(v - (float)hi);
    }
}

// ---------------- split-fp16 MFMA GEMM ---------------------------------------
// A: hi/lo fp16 (x16 scale), row stride lda halves. B: g_w16+boff, [N][K] (x64).
// C_logical = acc/1024. MODE 0: fp32 head-major out (QKV)
//             MODE 1: fp32 row-major + interleaved fp16-pair residual (O-proj)
//             MODE 2: relu -> fp16 hi/lo pair out (x16 scale) (FFN1)
//             MODE 3: fp32 row-major + fp32 residual (FFN2)
// Staging via global_load_lds width-16: dest = wave-uniform base + lane*16,
// which equals halves offset block*512 + l*8 == row-major [row16][32] layout.

template<int MODE>
__global__ __launch_bounds__(256, 2) void k_gemm16(
    const half_t* __restrict__ Ah, const half_t* __restrict__ Al, int lda,
    size_t boff_h, size_t boff_l,
    const float* __restrict__ bias,
    const void* __restrict__ res,
    void* __restrict__ out0, void* __restrict__ out1,
    int M, int N, int K) {
    __shared__ half_t sA[2][128 * 32];
    __shared__ half_t sB[2][128 * 32];
    const int tid = threadIdx.x;
    const int w = tid >> 6, l = tid & 63;
    const int row0 = blockIdx.y * 128, col0 = blockIdx.x * 128;
    const half_t* Bh = g_w16 + boff_h;
    const half_t* Bl = g_w16 + boff_l;

    const int srow = l >> 2;            // 0..15
    const int skk  = (l & 3) * 8;       // 0,8,16,24
    const int fr = l & 15, qk = (l >> 4) * 8;
    const int mh = (w >> 1) * 64, nh = (w & 1) * 64;

    f32x4 acc[4][4];
    #pragma unroll
    for (int i = 0; i < 4; ++i)
        #pragma unroll
        for (int j = 0; j < 4; ++j) acc[i][j] = (f32x4){0.f, 0.f, 0.f, 0.f};

    for (int k0 = 0; k0 < K; k0 += 32) {
        #pragma unroll
        for (int t = 0; t < 2; ++t) {
            int r = (w * 2 + t) * 16 + srow;
            int grA = row0 + r; if (grA >= M) grA = M - 1;
            int grB = col0 + r;
            half_t* da = (half_t*)&sA[0][(w * 2 + t) * 512];
            half_t* db = (half_t*)&sB[0][(w * 2 + t) * 512];
            half_t* da2 = (half_t*)&sA[1][(w * 2 + t) * 512];
            half_t* db2 = (half_t*)&sB[1][(w * 2 + t) * 512];
            gload16(Ah + (size_t)grA * lda + k0 + skk, da);
            gload16(Al + (size_t)grA * lda + k0 + skk, da2);
            gload16(Bh + (size_t)grB * K + k0 + skk, db);
            gload16(Bl + (size_t)grB * K + k0 + skk, db2);
        }
        __syncthreads();
        f16x8 a0[4], a1[4], b0[4], b1[4];
        #pragma unroll
        for (int i = 0; i < 4; ++i) {
            a0[i] = *(const f16x8*)&sA[0][(mh + i * 16 + fr) * 32 + qk];
            a1[i] = *(const f16x8*)&sA[1][(mh + i * 16 + fr) * 32 + qk];
            b0[i] = *(const f16x8*)&sB[0][(nh + i * 16 + fr) * 32 + qk];
            b1[i] = *(const f16x8*)&sB[1][(nh + i * 16 + fr) * 32 + qk];
        }
        #pragma unroll
        for (int i = 0; i < 4; ++i)
            #pragma unroll
            for (int j = 0; j < 4; ++j) {
                acc[i][j] = __builtin_amdgcn_mfma_f32_16x16x32_f16(a0[i], b0[j], acc[i][j], 0, 0, 0);
                acc[i][j] = __builtin_amdgcn_mfma_f32_16x16x32_f16(a0[i], b1[j], acc[i][j], 0, 0, 0);
                acc[i][j] = __builtin_amdgcn_mfma_f32_16x16x32_f16(a1[i], b0[j], acc[i][j], 0, 0, 0);
            }
        __syncthreads();
    }

    const float dsc = 1.0f / 1024.0f;
    #pragma unroll
    for (int i = 0; i < 4; ++i) {
        #pragma unroll
        for (int r = 0; r < 4; ++r) {
            int row = row0 + mh + i * 16 + ((l >> 4) << 2) + r;
            if (row >= M) continue;
            #pragma unroll
            for (int j = 0; j < 4; ++j) {
                int col = col0 + nh + j * 16 + (l & 15);
                float vv = acc[i][j][r] * dsc + bias[col];
                if (MODE == 0) {
                    int b = row / 255, wl = row - b * 255;
                    int h = col / 96, d = col - h * 96;
                    ((float*)out0)[(((size_t)b * 8 + h) * 255 + wl) * 96 + d] = vv;
                } else if (MODE == 1) {
                    const half_t* rp = (const half_t*)res;
                    vv += ((float)rp[(size_t)row * 1536 + col] +
                           (float)rp[(size_t)row * 1536 + 768 + col]) * 0.0625f;
                    ((float*)out0)[(size_t)row * N + col] = vv;
                } else if (MODE == 2) {
                    vv = fmaxf(vv, 0.f);
                    float t16 = vv * 16.f;
                    half_t hi = (half_t)t16;
                    ((half_t*)out0)[(size_t)row * N + col] = hi;
                    ((half_t*)out1)[(size_t)row * N + col] = (half_t)(t16 - (float)hi);
                } else {
                    vv += ((const float*)res)[(size_t)row * N + col];
                    ((float*)out0)[(size_t)row * N + col] = vv;
                }
            }
        }
    }
}

// ---------------- fused attention per (b,h), head-major q/k/v ----------------
// q/k/v: [B,H,W,96] fp32. ctx written fp32 head-major in-place over q.

__global__ __launch_bounds__(256) void k_attn(float* q, const float* __restrict__ kmat,
                                              const float* __restrict__ v) {
    const int bh = blockIdx.x;
    const int tid = threadIdx.x;
    __shared__ float qv[8][96];
    __shared__ float pT[256][12];      // [key][qj], stride 12 for fp32x4 alignment
    __shared__ float mrow[8], drow[8];
    __shared__ float4 part[10][8][24];
    const float scale = 0.10206207261596575f;  // 1/sqrt(96)
    const size_t base = (size_t)bh * Wn;

    for (int q0 = 0; q0 < Wn; q0 += 8) {
        // stage q tile
        for (int idx = tid; idx < 8 * 96; idx += 256) {
            int qj = idx / 96, d = idx % 96;
            int row = q0 + qj; if (row > Wn - 1) row = Wn - 1;
            qv[qj][d] = q[(base + row) * 96 + d];
        }
        __syncthreads();
        // scores: thread t = key t, contiguous 384B K rows (L2-resident)
        if (tid < Wn) {
            const float4* kp = (const float4*)(kmat + (base + tid) * 96);
            float s[8] = {0, 0, 0, 0, 0, 0, 0, 0};
            #pragma unroll 4
            for (int d4 = 0; d4 < 24; ++d4) {
                float4 kv = kp[d4];
                #pragma unroll
                for (int qj = 0; qj < 8; ++qj) {
                    const float4 q4 = *(const float4*)&qv[qj][d4 * 4];
                    s[qj] += kv.x * q4.x + kv.y * q4.y + kv.z * q4.z + kv.w * q4.w;
                }
            }
            float4 w0 = {s[0] * scale, s[1] * scale, s[2] * scale, s[3] * scale};
            float4 w1 = {s[4] * scale, s[5] * scale, s[6] * scale, s[7] * scale};
            *(float4*)&pT[tid][0] = w0;
            *(float4*)&pT[tid][4] = w1;
        }
        __syncthreads();
        {   // row max, 32-lane group per q-row
            int qj = tid >> 5, lane = tid & 31;
            float m = -3.0e38f;
            for (int t = lane; t < Wn; t += 32) m = fmaxf(m, pT[t][qj]);
            #pragma unroll
            for (int off = 16; off > 0; off >>= 1) m = fmaxf(m, __shfl_xor(m, off, 32));
            if (lane == 0) mrow[qj] = m;
        }
        __syncthreads();
        for (int idx = tid; idx < Wn * 8; idx += 256) {
            int t = idx >> 3, qj = idx & 7;
            pT[t][qj] = __expf(pT[t][qj] - mrow[qj]);
        }
        __syncthreads();
        {   // row sum
            int qj = tid >> 5, lane = tid & 31;
            float ssum = 0.0f;
            for (int t = lane; t < Wn; t += 32) ssum += pT[t][qj];
            #pragma unroll
            for (int off = 16; off > 0; off >>= 1) ssum += __shfl_xor(ssum, off, 32);
            if (lane == 0) drow[qj] = ssum;
        }
        __syncthreads();
        // ctx partials: 10 key-groups x 24 float4 lanes
        if (tid < 240) {
            int g = tid / 24, d4 = tid % 24;
            float4 acc8[8];
            #pragma unroll
            for (int qj = 0; qj < 8; ++qj) { acc8[qj].x = 0; acc8[qj].y = 0; acc8[qj].z = 0; acc8[qj].w = 0; }
            for (int t = g; t < Wn; t += 10) {
                const float4 vv = *(const float4*)(v + (base + t) * 96 + d4 * 4);
                const float4 p0 = *(const float4*)&pT[t][0];
                const float4 p1 = *(const float4*)&pT[t][4];
                acc8[0].x += p0.x * vv.x; acc8[0].y += p0.x * vv.y; acc8[0].z += p0.x * vv.z; acc8[0].w += p0.x * vv.w;
                acc8[1].x += p0.y * vv.x; acc8[1].y += p0.y * vv.y; acc8[1].z += p0.y * vv.z; acc8[1].w += p0.y * vv.w;
                acc8[2].x += p0.z * vv.x; acc8[2].y += p0.z * vv.y; acc8[2].z += p0.z * vv.z; acc8[2].w += p0.z * vv.w;
                acc8[3].x += p0.w * vv.x; acc8[3].y += p0.w * vv.y; acc8[3].z += p0.w * vv.z; acc8[3].w += p0.w * vv.w;
                acc8[4].x += p1.x * vv.x; acc8[4].y += p1.x * vv.y; acc8[4].z += p1.x * vv.z; acc8[4].w += p1.x * vv.w;
                acc8[5].x += p1.y * vv.x; acc8[5].y += p1.y * vv.y; acc8[5].z += p1.y * vv.z; acc8[5].w += p1.y * vv.w;
                acc8[6].x += p1.z * vv.x; acc8[6].y += p1.z * vv.y; acc8[6].z += p1.z * vv.z; acc8[6].w += p1.z * vv.w;
                acc8[7].x += p1.w * vv.x; acc8[7].y += p1.w * vv.y; acc8[7].z += p1.w * vv.z; acc8[7].w += p1.w * vv.w;
            }
            #pragma unroll
            for (int qj = 0; qj < 8; ++qj) part[g][qj][d4] = acc8[qj];
        }
        __syncthreads();
        if (tid < 192) {
            int qj = tid / 24, d4 = tid % 24;
            if (q0 + qj < Wn) {
                float4 s = {0, 0, 0, 0};
                #pragma unroll
                for (int g = 0; g < 10; ++g) {
                    float4 p = part[g][qj][d4];
                    s.x += p.x; s.y += p.y; s.z += p.z; s.w += p.w;
                }
                float inv = 1.0f / drow[qj];
                s.x *= inv; s.y *= inv; s.z *= inv; s.w *= inv;
                *(float4*)(q + (base + q0 + qj) * 96 + d4 * 4) = s;   // ctx in-place
            }
        }
        __syncthreads();
    }
}

// ---------------- ctx head-major fp32 -> interleaved fp16 pair, row-major ----
// FIX (round 4): must cover ALL B*H*W*24 float4s (3,133,440), not NROWS*24.
// Round 2/3 converted only 1/8 of ctx, leaving stale fp32-as-fp16 NaNs.

#define CTXF4 (Bsz * Hh * Wn * 24)   // 3,133,440

__global__ void k_ctx_split(const float4* __restrict__ chm, half_t* __restrict__ o) {
    int idx = blockIdx.x * 256 + threadIdx.x;   // over B*H*W*24
    if (idx >= CTXF4) return;
    float4 v = chm[idx];
    int c4 = idx % 24, tmp = idx / 24;          // tmp in [0, B*H*W)
    int wl = tmp % 255, bh = tmp / 255;         // bh in [0, 512)
    int b = bh >> 3, h = bh & 7;
    size_t r = (size_t)b * 255 + wl;
    size_t off = r * 1536 + h * 96 + c4 * 4;
    float a0 = v.x * 16.f, a1 = v.y * 16.f, a2 = v.z * 16.f, a3 = v.w * 16.f;
    half_t h0 = (half_t)a0, h1 = (half_t)a1, h2 = (half_t)a2, h3 = (half_t)a3;
    f16x4 hv = {h0, h1, h2, h3};
    f16x4 lv = {(half_t)(a0 - (float)h0), (half_t)(a1 - (float)h1),
                (half_t)(a2 - (float)h2), (half_t)(a3 - (float)h3)};
    *(f16x4*)&o[off] = hv;
    *(f16x4*)&o[off + 768] = lv;
}

// ---------------- row LayerNorm (optional fused fp16-pair split output) -----

template<int SPLIT>
__global__ __launch_bounds__(256) void k_ln(const float* __restrict__ X, const float* __restrict__ g,
                                            const float* __restrict__ bt, float* __restrict__ Y,
                                            half_t* __restrict__ Y16) {
    const int r = blockIdx.x, tid = threadIdx.x;
    __shared__ float red[256];
    const float* x = X + (size_t)r * Dd;
    float x0 = x[tid], x1 = x[tid + 256], x2 = x[tid + 512];
    red[tid] = x0 + x1 + x2; __syncthreads();
    for (int s = 128; s > 0; s >>= 1) { if (tid < s) red[tid] += red[tid + s]; __syncthreads(); }
    float mean = red[0] * (1.0f / 768.0f);
    __syncthreads();
    float d0 = x0 - mean, d1 = x1 - mean, d2 = x2 - mean;
    red[tid] = d0 * d0 + d1 * d1 + d2 * d2; __syncthreads();
    for (int s = 128; s > 0; s >>= 1) { if (tid < s) red[tid] += red[tid + s]; __syncthreads(); }
    float rs = rsqrtf(red[0] * (1.0f / 768.0f) + 1e-5f);
    float* y = Y + (size_t)r * Dd;
    float y0 = d0 * rs * g[tid]       + bt[tid];
    float y1 = d1 * rs * g[tid + 256] + bt[tid + 256];
    float y2 = d2 * rs * g[tid + 512] + bt[tid + 512];
    y[tid] = y0; y[tid + 256] = y1; y[tid + 512] = y2;
    if (SPLIT) {
        half_t* h = Y16 + (size_t)r * 1536;
        float t0 = y0 * 16.f, t1 = y1 * 16.f, t2 = y2 * 16.f;
        half_t h0 = (half_t)t0, h1 = (half_t)t1, h2 = (half_t)t2;
        h[tid] = h0; h[tid + 256] = h1; h[tid + 512] = h2;
        h[768 + tid] = (half_t)(t0 - (float)h0);
        h[768 + tid + 256] = (half_t)(t1 - (float)h1);
        h[768 + tid + 512] = (half_t)(t2 - (float)h2);
    }
}

// ---------------- final LN + 2-class linear + softmax + argmax --------------

__global__ __launch_bounds__(256) void k_final(const float* __restrict__ X, const float* __restrict__ g,
                                               const float* __restrict__ bt, const float* __restrict__ lw,
                                               const float* __restrict__ lb, float* __restrict__ out) {
    const int r = blockIdx.x, tid = threadIdx.x;
    __shared__ float red[256];
    const float* x = X + (size_t)r * Dd;
    float x0 = x[tid], x1 = x[tid + 256], x2 = x[tid + 512];
    red[tid] = x0 + x1 + x2; __syncthreads();
    for (int s = 128; s > 0; s >>= 1) { if (tid < s) red[tid] += red[tid + s]; __syncthreads(); }
    float mean = red[0] * (1.0f / 768.0f);
    __syncthreads();
    float d0 = x0 - mean, d1 = x1 - mean, d2 = x2 - mean;
    red[tid] = d0 * d0 + d1 * d1 + d2 * d2; __syncthreads();
    for (int s = 128; s > 0; s >>= 1) { if (tid < s) red[tid] += red[tid + s]; __syncthreads(); }
    float rs = rsqrtf(red[0] * (1.0f / 768.0f) + 1e-5f);
    __syncthreads();
    float n0 = d0 * rs * g[tid]       + bt[tid];
    float n1 = d1 * rs * g[tid + 256] + bt[tid + 256];
    float n2 = d2 * rs * g[tid + 512] + bt[tid + 512];
    float l0 = n0 * lw[2 * tid]     + n1 * lw[2 * (tid + 256)]     + n2 * lw[2 * (tid + 512)];
    float l1 = n0 * lw[2 * tid + 1] + n1 * lw[2 * (tid + 256) + 1] + n2 * lw[2 * (tid + 512) + 1];
    red[tid] = l0; __syncthreads();
    for (int s = 128; s > 0; s >>= 1) { if (tid < s) red[tid] += red[tid + s]; __syncthreads(); }
    l0 = red[0]; __syncthreads();
    red[tid] = l1; __syncthreads();
    for (int s = 128; s > 0; s >>= 1) { if (tid < s) red[tid] += red[tid + s]; __syncthreads(); }
    l1 = red[0];
    if (tid == 0) {
        l0 += lb[0]; l1 += lb[1];
        float m = fmaxf(l0, l1);
        float e0 = expf(l0 - m), e1 = expf(l1 - m);
        float inv = 1.0f / (e0 + e1);
        out[2 * r] = e0 * inv;
        out[2 * r + 1] = e1 * inv;
        out[2 * NROWS + r] = (l1 > l0) ? 1.0f : 0.0f;   // tie -> first index (0)
    }
}

// ---------------- launch --------------------------------------------------

extern "C" void kernel_launch(void* const* d_in, const int* in_sizes, int n_in,
                              void* d_out, int out_size, void* d_ws, size_t ws_size,
                              hipStream_t stream) {
    const float* ob  = (const float*)d_in[0];
    const int*   wid = (const int*)d_in[1];
    const float* Wq  = (const float*)d_in[2];  const float* bq  = (const float*)d_in[3];
    const float* Wk  = (const float*)d_in[4];  const float* bk  = (const float*)d_in[5];
    const float* Wv  = (const float*)d_in[6];  const float* bv  = (const float*)d_in[7];
    const float* Wo  = (const float*)d_in[8];  const float* bo  = (const float*)d_in[9];
    const float* g1  = (const float*)d_in[10]; const float* b1  = (const float*)d_in[11];
    const float* W1f = (const float*)d_in[12]; const float* b1f = (const float*)d_in[13];
    const float* W2f = (const float*)d_in[14]; const float* b2f = (const float*)d_in[15];
    const float* g2  = (const float*)d_in[16]; const float* b2  = (const float*)d_in[17];
    const float* ng  = (const float*)d_in[18]; const float* nb  = (const float*)d_in[19];
    const float* lw  = (const float*)d_in[20]; const float* lb  = (const float*)d_in[21];
    float* out = (float*)d_out;

    char* ws = (char*)d_ws;
    const size_t MB = 1u << 20;
    const size_t SLOT = 48 * MB;               // 50,331,648 >= 50,135,040 needed per slot
    int* fi = (int*)ws;                        // 65,280 B
    char* S1 = ws + MB;
    char* S2 = S1 + SLOT;
    char* S3 = S2 + SLOT;
    char* S4 = S3 + SLOT;                      // total 193 MiB (round-1's 201 MiB proven OK)

    half_t* feat16 = (half_t*)S1;              // interleaved hi|lo, row = 1536 halves
    float*  q_hm   = (float*)S2;               // [B,H,W,96] -> ctx in-place
    float*  k_hm   = (float*)S3;
    float*  v_hm   = (float*)S4;
    half_t* ctx16  = (half_t*)S3;              // after attention (k consumed)
    float*  t1     = (float*)S2;               // after ctx_split (q/ctx consumed)
    float*  xbuf   = (float*)S4;               // LN1 out (v consumed)
    half_t* x16    = (half_t*)S3;              // LN1 split out (ctx16 consumed)
    half_t* ffh_h  = (half_t*)S1;              // per-chunk hidden hi (feat16 consumed)
    half_t* ffh_l  = (half_t*)S2;              // per-chunk hidden lo (t1 consumed)
    float*  t2     = (float*)S3;               // overlays consumed x16 records row-by-row
    float*  x2     = (float*)S1;               // LN2 out (ffh_h consumed)

    // weight prep (split-fp16, transposed, x64) into static device memory
    k_wsplit<<<dim3(24, 24), dim3(32, 8), 0, stream>>>(Wq, 768, 768, OFF_WQ_H, OFF_WQ_L);
    k_wsplit<<<dim3(24, 24), dim3(32, 8), 0, stream>>>(Wk, 768, 768, OFF_WK_H, OFF_WK_L);
    k_wsplit<<<dim3(24, 24), dim3(32, 8), 0, stream>>>(Wv, 768, 768, OFF_WV_H, OFF_WV_L);
    k_wsplit<<<dim3(24, 24), dim3(32, 8), 0, stream>>>(Wo, 768, 768, OFF_WO_H, OFF_WO_L);
    k_wsplit<<<dim3(96, 24), dim3(32, 8), 0, stream>>>(W1f, 768, 3072, OFF_W1_H, OFF_W1_L);
    k_wsplit<<<dim3(24, 96), dim3(32, 8), 0, stream>>>(W2f, 3072, 768, OFF_W2_H, OFF_W2_L);

    k_init_fi<<<(Bsz * Wn + 255) / 256, 256, 0, stream>>>(fi);
    k_scan<<<(Bsz * Tt) / 256, 256, 0, stream>>>(wid, fi);
    k_gather<<<(NROWS * 192 + 255) / 256, 256, 0, stream>>>((const float4*)ob, fi, feat16);

    // QKV GEMMs -> head-major fp32
    dim3 gqkv(6, 128);
    k_gemm16<0><<<gqkv, 256, 0, stream>>>(feat16, feat16 + 768, 1536, OFF_WQ_H, OFF_WQ_L,
                                          bq, nullptr, q_hm, nullptr, NROWS, Dd, Dd);
    k_gemm16<0><<<gqkv, 256, 0, stream>>>(feat16, feat16 + 768, 1536, OFF_WK_H, OFF_WK_L,
                                          bk, nullptr, k_hm, nullptr, NROWS, Dd, Dd);
    k_gemm16<0><<<gqkv, 256, 0, stream>>>(feat16, feat16 + 768, 1536, OFF_WV_H, OFF_WV_L,
                                          bv, nullptr, v_hm, nullptr, NROWS, Dd, Dd);

    k_attn<<<Bsz * Hh, 256, 0, stream>>>(q_hm, k_hm, v_hm);     // ctx overwrites q

    k_ctx_split<<<(CTXF4 + 255) / 256, 256, 0, stream>>>((const float4*)q_hm, ctx16);

    // t1 = feat + ctx@Wo + bo ; x = LN1(t1) (+ split x16)
    k_gemm16<1><<<gqkv, 256, 0, stream>>>(ctx16, ctx16 + 768, 1536, OFF_WO_H, OFF_WO_L,
                                          bo, feat16, t1, nullptr, NROWS, Dd, Dd);
    k_ln<1><<<NROWS, 256, 0, stream>>>(t1, g1, b1, xbuf, x16);

    // FFN in 2 row-chunks of 8160
    for (int c = 0; c < 2; ++c) {
        const int r0 = c * 8160, mc = 8160;
        dim3 gf1(24, 64);
        k_gemm16<2><<<gf1, 256, 0, stream>>>(x16 + (size_t)r0 * 1536, x16 + (size_t)r0 * 1536 + 768, 1536,
                                             OFF_W1_H, OFF_W1_L, b1f, nullptr,
                                             ffh_h, ffh_l, mc, 3072, Dd);
        dim3 gf2(6, 64);
        k_gemm16<3><<<gf2, 256, 0, stream>>>(ffh_h, ffh_l, 3072,
                                             OFF_W2_H, OFF_W2_L, b2f, xbuf + (size_t)r0 * Dd,
                                             t2 + (size_t)r0 * Dd, nullptr, mc, Dd, 3072);
    }

    k_ln<0><<<NROWS, 256, 0, stream>>>(t2, g2, b2, x2, nullptr);
    k_final<<<NROWS, 256, 0, stream>>>(x2, ng, nb, lw, lb, out);
}

// Round 5
// 1351.500 us; speedup vs baseline: 3.0761x; 1.3367x over previous
//
#include <hip/hip_runtime.h>
#include <cmath>

#define Bsz 64
#define Tt  512
#define Dd  768
#define Wn  255
#define Hh  8
#define DHd 96
#define NROWS (Bsz*Wn)   // 16320

typedef _Float16 half_t;
typedef _Float16 f16x8 __attribute__((ext_vector_type(8)));
typedef _Float16 f16x4 __attribute__((ext_vector_type(4)));
typedef float f32x4 __attribute__((ext_vector_type(4)));

// ---- split-fp16 weights (transposed [N][K]), ~27 MiB static device memory ----
// scales: weights x64, activations x16, GEMM epilogue descales by 1/1024.
#define OFF_WQ_H 0
#define OFF_WQ_L 589824
#define OFF_WK_H 1179648
#define OFF_WK_L 1769472
#define OFF_WV_H 2359296
#define OFF_WV_L 2949120
#define OFF_WO_H 3538944
#define OFF_WO_L 4128768
#define OFF_W1_H 4718592
#define OFF_W1_L 7077888
#define OFF_W2_H 9437184
#define OFF_W2_L 11796480
__device__ __align__(16) half_t g_w16[14155776];

__device__ __forceinline__ void gload16(const half_t* g, half_t* l) {
    __builtin_amdgcn_global_load_lds((const __attribute__((address_space(1))) void*)g,
                                     (__attribute__((address_space(3))) void*)l, 16, 0, 0);
}

// ---------------- gather: first-subtoken index + feature copy ----------------

__global__ void k_init_fi(int* fi) {
    int i = blockIdx.x * 256 + threadIdx.x;
    if (i < Bsz * Wn) fi[i] = 0x7fffffff;
}

__global__ void k_scan(const int* __restrict__ wid, int* __restrict__ fi) {
    int i = blockIdx.x * 256 + threadIdx.x;   // over B*T
    if (i >= Bsz * Tt) return;
    int b = i / Tt, t = i % Tt;
    int w = wid[i];
    if (w >= 0 && w < Wn) atomicMin(&fi[b * Wn + w], t);
}

// gather directly into interleaved fp16 hi/lo records (row = 1536 halves: hi[768]|lo[768])
__global__ void k_gather(const float4* __restrict__ ob, const int* __restrict__ fi,
                         half_t* __restrict__ f16) {
    int i = blockIdx.x * 256 + threadIdx.x;   // over NROWS*192
    if (i >= NROWS * 192) return;
    int r = i / 192, c = i % 192;
    int b = r / Wn;
    int idx = fi[r];
    if (idx == 0x7fffffff) idx = 0;           // argmax(all-False) == 0
    float4 v = ob[((size_t)b * Tt + idx) * 192 + c];
    float a0 = v.x * 16.f, a1 = v.y * 16.f, a2 = v.z * 16.f, a3 = v.w * 16.f;
    half_t h0 = (half_t)a0, h1 = (half_t)a1, h2 = (half_t)a2, h3 = (half_t)a3;
    f16x4 hv = {h0, h1, h2, h3};
    f16x4 lv = {(half_t)(a0 - (float)h0), (half_t)(a1 - (float)h1),
                (half_t)(a2 - (float)h2), (half_t)(a3 - (float)h3)};
    size_t off = (size_t)r * 1536 + c * 4;
    *(f16x4*)&f16[off] = hv;
    *(f16x4*)&f16[off + 768] = lv;
}

// ---------------- weight transpose + split: W[K,N] -> WT_h/WT_l [N,K] x64 ----

__global__ void k_wsplit(const float* __restrict__ Wm, int K, int N,
                         size_t off_h, size_t off_l) {
    __shared__ float sm[32][33];
    const int tx = threadIdx.x, ty = threadIdx.y;
    const int n0 = blockIdx.x * 32, k0 = blockIdx.y * 32;
    #pragma unroll
    for (int r = 0; r < 4; ++r)
        sm[ty + r * 8][tx] = Wm[(size_t)(k0 + ty + r * 8) * N + n0 + tx];
    __syncthreads();
    half_t* oh = g_w16 + off_h;
    half_t* ol = g_w16 + off_l;
    #pragma unroll
    for (int r = 0; r < 4; ++r) {
        float v = 64.f * sm[tx][ty + r * 8];
        half_t hi = (half_t)v;
        size_t o = (size_t)(n0 + ty + r * 8) * K + k0 + tx;
        oh[o] = hi;
        ol[o] = (half_t)(v - (float)hi);
    }
}

// ---------------- split-fp16 MFMA GEMM ---------------------------------------
// A: hi/lo fp16 (x16 scale). AMODE 0: linear rows, stride lda halves.
//                            AMODE 1: head-major ctx [bh][256][hi96|lo96].
// B: g_w16+boff, [N][K] (x64). C_logical = acc/1024.
// MODE 0: fp16 hi/lo pair x16, head-major [bh][256][hi96|lo96] (Q,K)
// MODE 4: fp16 hi/lo pair x16, V transposed [bh][2][96][256]
// MODE 1: fp32 row-major + interleaved fp16-pair residual (O-proj)
// MODE 2: relu -> fp16 hi/lo pair out x16 (FFN1)
// MODE 3: fp32 row-major + fp32 residual (FFN2)

template<int MODE, int AMODE>
__global__ __launch_bounds__(256, 2) void k_gemm16(
    const half_t* __restrict__ Ah, const half_t* __restrict__ Al, int lda,
    size_t boff_h, size_t boff_l,
    const float* __restrict__ bias,
    const void* __restrict__ res,
    void* __restrict__ out0, void* __restrict__ out1,
    int M, int N, int K) {
    __shared__ half_t sA[2][128 * 32];
    __shared__ half_t sB[2][128 * 32];
    const int tid = threadIdx.x;
    const int w = tid >> 6, l = tid & 63;
    const int row0 = blockIdx.y * 128, col0 = blockIdx.x * 128;
    const half_t* Bh = g_w16 + boff_h;
    const half_t* Bl = g_w16 + boff_l;

    const int srow = l >> 2;            // 0..15
    const int skk  = (l & 3) * 8;       // 0,8,16,24
    const int fr = l & 15, qk = (l >> 4) * 8;
    const int mh = (w >> 1) * 64, nh = (w & 1) * 64;

    f32x4 acc[4][4];
    #pragma unroll
    for (int i = 0; i < 4; ++i)
        #pragma unroll
        for (int j = 0; j < 4; ++j) acc[i][j] = (f32x4){0.f, 0.f, 0.f, 0.f};

    for (int k0 = 0; k0 < K; k0 += 32) {
        #pragma unroll
        for (int t = 0; t < 2; ++t) {
            int r = (w * 2 + t) * 16 + srow;
            int grA = row0 + r; if (grA >= M) grA = M - 1;
            int grB = col0 + r;
            half_t* da = (half_t*)&sA[0][(w * 2 + t) * 512];
            half_t* db = (half_t*)&sB[0][(w * 2 + t) * 512];
            half_t* da2 = (half_t*)&sA[1][(w * 2 + t) * 512];
            half_t* db2 = (half_t*)&sB[1][(w * 2 + t) * 512];
            if (AMODE == 1) {
                int b = grA / 255, wl = grA - b * 255;
                int kk = k0 + skk;
                int h = kk / 96, d = kk - h * 96;
                size_t aoff = ((size_t)(b * 8 + h) * 256 + wl) * 192 + d;
                gload16(Ah + aoff, da);
                gload16(Al + aoff, da2);
            } else {
                gload16(Ah + (size_t)grA * lda + k0 + skk, da);
                gload16(Al + (size_t)grA * lda + k0 + skk, da2);
            }
            gload16(Bh + (size_t)grB * K + k0 + skk, db);
            gload16(Bl + (size_t)grB * K + k0 + skk, db2);
        }
        __syncthreads();
        f16x8 a0[4], a1[4], b0[4], b1[4];
        #pragma unroll
        for (int i = 0; i < 4; ++i) {
            a0[i] = *(const f16x8*)&sA[0][(mh + i * 16 + fr) * 32 + qk];
            a1[i] = *(const f16x8*)&sA[1][(mh + i * 16 + fr) * 32 + qk];
            b0[i] = *(const f16x8*)&sB[0][(nh + i * 16 + fr) * 32 + qk];
            b1[i] = *(const f16x8*)&sB[1][(nh + i * 16 + fr) * 32 + qk];
        }
        #pragma unroll
        for (int i = 0; i < 4; ++i)
            #pragma unroll
            for (int j = 0; j < 4; ++j) {
                acc[i][j] = __builtin_amdgcn_mfma_f32_16x16x32_f16(a0[i], b0[j], acc[i][j], 0, 0, 0);
                acc[i][j] = __builtin_amdgcn_mfma_f32_16x16x32_f16(a0[i], b1[j], acc[i][j], 0, 0, 0);
                acc[i][j] = __builtin_amdgcn_mfma_f32_16x16x32_f16(a1[i], b0[j], acc[i][j], 0, 0, 0);
            }
        __syncthreads();
    }

    const float dsc = 1.0f / 1024.0f;
    #pragma unroll
    for (int i = 0; i < 4; ++i) {
        #pragma unroll
        for (int r = 0; r < 4; ++r) {
            int row = row0 + mh + i * 16 + ((l >> 4) << 2) + r;
            if (row >= M) continue;
            #pragma unroll
            for (int j = 0; j < 4; ++j) {
                int col = col0 + nh + j * 16 + (l & 15);
                float vv = acc[i][j][r] * dsc + bias[col];
                if (MODE == 0 || MODE == 4) {
                    int b = row / 255, wl = row - b * 255;
                    int h = col / 96, d = col - h * 96;
                    float t16 = vv * 16.f;
                    half_t hi = (half_t)t16;
                    half_t lo = (half_t)(t16 - (float)hi);
                    if (MODE == 0) {
                        size_t o = ((size_t)(b * 8 + h) * 256 + wl) * 192 + d;
                        ((half_t*)out0)[o] = hi;
                        ((half_t*)out0)[o + 96] = lo;
                    } else {
                        size_t o = (size_t)(b * 8 + h) * 49152 + (size_t)d * 256 + wl;
                        ((half_t*)out0)[o] = hi;
                        ((half_t*)out0)[o + 24576] = lo;
                    }
                } else if (MODE == 1) {
                    const half_t* rp = (const half_t*)res;
                    vv += ((float)rp[(size_t)row * 1536 + col] +
                           (float)rp[(size_t)row * 1536 + 768 + col]) * 0.0625f;
                    ((float*)out0)[(size_t)row * N + col] = vv;
                } else if (MODE == 2) {
                    vv = fmaxf(vv, 0.f);
                    float t16 = vv * 16.f;
                    half_t hi = (half_t)t16;
                    ((half_t*)out0)[(size_t)row * N + col] = hi;
                    ((half_t*)out1)[(size_t)row * N + col] = (half_t)(t16 - (float)hi);
                } else {
                    vv += ((const float*)res)[(size_t)row * N + col];
                    ((float*)out0)[(size_t)row * N + col] = vv;
                }
            }
        }
    }
}

// ---------------- flash MFMA attention, split-fp16, one block per (b,h) ------
// q/ctx: [bh][256][hi96|lo96] x16; k same; vT: [bh][2][96][256] x16.
// ctx overwrites q in-place (per-wave rows, read-before-write within tile).

__global__ __launch_bounds__(256, 2) void k_attn2(half_t* __restrict__ qc,
                                                  const half_t* __restrict__ kk16,
                                                  const half_t* __restrict__ vt16) {
    __shared__ half_t sK[64][200];      // [key][hi96|lo96], pad 200 (stride%32banks=4)
    __shared__ half_t sVT[192][72];     // [(plane*96+dim)][key64], pad 72
    __shared__ float  sP[4][16][68];    // per-wave P [qrow][key], pad 68
    const int tid = threadIdx.x;
    const int w = tid >> 6, l = tid & 63;
    const int lr = l & 15, lc = l >> 4;
    const size_t base = (size_t)blockIdx.x * 49152;
    const float ssc = 0.10206207261596575f / 256.0f;   // 1/sqrt(96) / (16*16)

    for (int qt = 0; qt < 4; ++qt) {
        const int qrow0 = qt * 64 + w * 16;
        f16x8 qf[2][3];
        #pragma unroll
        for (int p = 0; p < 2; ++p)
            #pragma unroll
            for (int s = 0; s < 3; ++s)
                qf[p][s] = *(const f16x8*)(qc + base + (size_t)(qrow0 + lr) * 192
                                           + p * 96 + s * 32 + lc * 8);
        f32x4 O[6];
        #pragma unroll
        for (int dn = 0; dn < 6; ++dn) O[dn] = (f32x4){0.f, 0.f, 0.f, 0.f};
        float mrow[4] = {-3e38f, -3e38f, -3e38f, -3e38f};
        float lrow[4] = {0.f, 0.f, 0.f, 0.f};

        for (int kt = 0; kt < 4; ++kt) {
            __syncthreads();                                   // slabs free to overwrite
            #pragma unroll
            for (int c = 0; c < 6; ++c) {                      // stage K tile
                int ch = w + c * 4;                            // 0..23
                *(f16x8*)&sK[l][ch * 8] =
                    *(const f16x8*)(kk16 + base + (size_t)(kt * 64 + l) * 192 + ch * 8);
            }
            #pragma unroll
            for (int c = 0; c < 6; ++c) {                      // stage V^T tile
                int u = c * 256 + tid;                         // 0..1535
                int pd = u >> 3, ch = u & 7;                   // pd=plane*96+dim
                *(f16x8*)&sVT[pd][ch * 8] =
                    *(const f16x8*)(vt16 + base + (size_t)pd * 256 + kt * 64 + ch * 8);
            }
            __syncthreads();
            // ---- S = Q K^T (split-fp16: qh*kh + qh*kl + ql*kh) ----
            f32x4 sacc[4];
            #pragma unroll
            for (int nt = 0; nt < 4; ++nt) sacc[nt] = (f32x4){0.f, 0.f, 0.f, 0.f};
            #pragma unroll
            for (int s = 0; s < 3; ++s)
                #pragma unroll
                for (int nt = 0; nt < 4; ++nt) {
                    f16x8 kh = *(const f16x8*)&sK[nt * 16 + lr][s * 32 + lc * 8];
                    f16x8 klo = *(const f16x8*)&sK[nt * 16 + lr][96 + s * 32 + lc * 8];
                    sacc[nt] = __builtin_amdgcn_mfma_f32_16x16x32_f16(qf[0][s], kh, sacc[nt], 0, 0, 0);
                    sacc[nt] = __builtin_amdgcn_mfma_f32_16x16x32_f16(qf[0][s], klo, sacc[nt], 0, 0, 0);
                    sacc[nt] = __builtin_amdgcn_mfma_f32_16x16x32_f16(qf[1][s], kh, sacc[nt], 0, 0, 0);
                }
            // ---- scale + mask + online softmax (C-layout: row=lc*4+r, col=lr) ----
            float sv[4][4], mx[4] = {-3e38f, -3e38f, -3e38f, -3e38f};
            #pragma unroll
            for (int nt = 0; nt < 4; ++nt) {
                int key = kt * 64 + nt * 16 + lr;
                #pragma unroll
                for (int r = 0; r < 4; ++r) {
                    float s_ = sacc[nt][r] * ssc;
                    if (key >= 255) s_ = -3e38f;
                    sv[nt][r] = s_;
                    mx[r] = fmaxf(mx[r], s_);
                }
            }
            #pragma unroll
            for (int r = 0; r < 4; ++r) {
                mx[r] = fmaxf(mx[r], __shfl_xor(mx[r], 1));
                mx[r] = fmaxf(mx[r], __shfl_xor(mx[r], 2));
                mx[r] = fmaxf(mx[r], __shfl_xor(mx[r], 4));
                mx[r] = fmaxf(mx[r], __shfl_xor(mx[r], 8));
            }
            float alpha[4], rs[4];
            #pragma unroll
            for (int r = 0; r < 4; ++r) {
                float mn = fmaxf(mrow[r], mx[r]);
                alpha[r] = __expf(mrow[r] - mn);
                mrow[r] = mn;
                rs[r] = 0.f;
            }
            float pv[4][4];
            #pragma unroll
            for (int nt = 0; nt < 4; ++nt)
                #pragma unroll
                for (int r = 0; r < 4; ++r) {
                    float p = __expf(sv[nt][r] - mrow[r]);
                    pv[nt][r] = p;
                    rs[r] += p;
                }
            #pragma unroll
            for (int r = 0; r < 4; ++r) {
                rs[r] += __shfl_xor(rs[r], 1);
                rs[r] += __shfl_xor(rs[r], 2);
                rs[r] += __shfl_xor(rs[r], 4);
                rs[r] += __shfl_xor(rs[r], 8);
                lrow[r] = lrow[r] * alpha[r] + rs[r];
            }
            #pragma unroll
            for (int dn = 0; dn < 6; ++dn)
                #pragma unroll
                for (int r = 0; r < 4; ++r) O[dn][r] *= alpha[r];
            // ---- P via LDS (wave-private), then O += P V ----
            #pragma unroll
            for (int nt = 0; nt < 4; ++nt)
                #pragma unroll
                for (int r = 0; r < 4; ++r)
                    sP[w][lc * 4 + r][nt * 16 + lr] = pv[nt][r];
            #pragma unroll
            for (int ks = 0; ks < 2; ++ks) {
                const float* pp = &sP[w][lr][ks * 32 + lc * 8];
                f16x8 ph, pl;
                #pragma unroll
                for (int j = 0; j < 8; ++j) {
                    float p = pp[j];
                    half_t h_ = (half_t)p;
                    ph[j] = h_;
                    pl[j] = (half_t)(p - (float)h_);
                }
                #pragma unroll
                for (int dn = 0; dn < 6; ++dn) {
                    f16x8 vh = *(const f16x8*)&sVT[dn * 16 + lr][ks * 32 + lc * 8];
                    f16x8 vl = *(const f16x8*)&sVT[96 + dn * 16 + lr][ks * 32 + lc * 8];
                    O[dn] = __builtin_amdgcn_mfma_f32_16x16x32_f16(ph, vh, O[dn], 0, 0, 0);
                    O[dn] = __builtin_amdgcn_mfma_f32_16x16x32_f16(ph, vl, O[dn], 0, 0, 0);
                    O[dn] = __builtin_amdgcn_mfma_f32_16x16x32_f16(pl, vh, O[dn], 0, 0, 0);
                }
            }
        }
        // ---- epilogue: ctx(x16) = O / l, fp16 hi/lo in-place over q ----
        #pragma unroll
        for (int r = 0; r < 4; ++r) {
            int qrow = qrow0 + lc * 4 + r;
            if (qrow >= Wn) continue;
            float inv = 1.0f / lrow[r];
            #pragma unroll
            for (int dn = 0; dn < 6; ++dn) {
                float val = O[dn][r] * inv;
                half_t hi = (half_t)val;
                half_t lo = (half_t)(val - (float)hi);
                size_t o = base + (size_t)qrow * 192 + dn * 16 + lr;
                qc[o] = hi;
                qc[o + 96] = lo;
            }
        }
    }
}

// ---------------- row LayerNorm (optional fused fp16-pair split output) -----

template<int SPLIT>
__global__ __launch_bounds__(256) void k_ln(const float* __restrict__ X, const float* __restrict__ g,
                                            const float* __restrict__ bt, float* __restrict__ Y,
                                            half_t* __restrict__ Y16) {
    const int r = blockIdx.x, tid = threadIdx.x;
    __shared__ float red[256];
    const float* x = X + (size_t)r * Dd;
    float x0 = x[tid], x1 = x[tid + 256], x2 = x[tid + 512];
    red[tid] = x0 + x1 + x2; __syncthreads();
    for (int s = 128; s > 0; s >>= 1) { if (tid < s) red[tid] += red[tid + s]; __syncthreads(); }
    float mean = red[0] * (1.0f / 768.0f);
    __syncthreads();
    float d0 = x0 - mean, d1 = x1 - mean, d2 = x2 - mean;
    red[tid] = d0 * d0 + d1 * d1 + d2 * d2; __syncthreads();
    for (int s = 128; s > 0; s >>= 1) { if (tid < s) red[tid] += red[tid + s]; __syncthreads(); }
    float rs = rsqrtf(red[0] * (1.0f / 768.0f) + 1e-5f);
    float* y = Y + (size_t)r * Dd;
    float y0 = d0 * rs * g[tid]       + bt[tid];
    float y1 = d1 * rs * g[tid + 256] + bt[tid + 256];
    float y2 = d2 * rs * g[tid + 512] + bt[tid + 512];
    y[tid] = y0; y[tid + 256] = y1; y[tid + 512] = y2;
    if (SPLIT) {
        half_t* h = Y16 + (size_t)r * 1536;
        float t0 = y0 * 16.f, t1 = y1 * 16.f, t2 = y2 * 16.f;
        half_t h0 = (half_t)t0, h1 = (half_t)t1, h2 = (half_t)t2;
        h[tid] = h0; h[tid + 256] = h1; h[tid + 512] = h2;
        h[768 + tid] = (half_t)(t0 - (float)h0);
        h[768 + tid + 256] = (half_t)(t1 - (float)h1);
        h[768 + tid + 512] = (half_t)(t2 - (float)h2);
    }
}

// ---------------- final LN + 2-class linear + softmax + argmax --------------

__global__ __launch_bounds__(256) void k_final(const float* __restrict__ X, const float* __restrict__ g,
                                               const float* __restrict__ bt, const float* __restrict__ lw,
                                               const float* __restrict__ lb, float* __restrict__ out) {
    const int r = blockIdx.x, tid = threadIdx.x;
    __shared__ float red[256];
    const float* x = X + (size_t)r * Dd;
    float x0 = x[tid], x1 = x[tid + 256], x2 = x[tid + 512];
    red[tid] = x0 + x1 + x2; __syncthreads();
    for (int s = 128; s > 0; s >>= 1) { if (tid < s) red[tid] += red[tid + s]; __syncthreads(); }
    float mean = red[0] * (1.0f / 768.0f);
    __syncthreads();
    float d0 = x0 - mean, d1 = x1 - mean, d2 = x2 - mean;
    red[tid] = d0 * d0 + d1 * d1 + d2 * d2; __syncthreads();
    for (int s = 128; s > 0; s >>= 1) { if (tid < s) red[tid] += red[tid + s]; __syncthreads(); }
    float rs = rsqrtf(red[0] * (1.0f / 768.0f) + 1e-5f);
    __syncthreads();
    float n0 = d0 * rs * g[tid]       + bt[tid];
    float n1 = d1 * rs * g[tid + 256] + bt[tid + 256];
    float n2 = d2 * rs * g[tid + 512] + bt[tid + 512];
    float l0 = n0 * lw[2 * tid]     + n1 * lw[2 * (tid + 256)]     + n2 * lw[2 * (tid + 512)];
    float l1 = n0 * lw[2 * tid + 1] + n1 * lw[2 * (tid + 256) + 1] + n2 * lw[2 * (tid + 512) + 1];
    red[tid] = l0; __syncthreads();
    for (int s = 128; s > 0; s >>= 1) { if (tid < s) red[tid] += red[tid + s]; __syncthreads(); }
    l0 = red[0]; __syncthreads();
    red[tid] = l1; __syncthreads();
    for (int s = 128; s > 0; s >>= 1) { if (tid < s) red[tid] += red[tid + s]; __syncthreads(); }
    l1 = red[0];
    if (tid == 0) {
        l0 += lb[0]; l1 += lb[1];
        float m = fmaxf(l0, l1);
        float e0 = expf(l0 - m), e1 = expf(l1 - m);
        float inv = 1.0f / (e0 + e1);
        out[2 * r] = e0 * inv;
        out[2 * r + 1] = e1 * inv;
        out[2 * NROWS + r] = (l1 > l0) ? 1.0f : 0.0f;   // tie -> first index (0)
    }
}

// ---------------- launch --------------------------------------------------

extern "C" void kernel_launch(void* const* d_in, const int* in_sizes, int n_in,
                              void* d_out, int out_size, void* d_ws, size_t ws_size,
                              hipStream_t stream) {
    const float* ob  = (const float*)d_in[0];
    const int*   wid = (const int*)d_in[1];
    const float* Wq  = (const float*)d_in[2];  const float* bq  = (const float*)d_in[3];
    const float* Wk  = (const float*)d_in[4];  const float* bk  = (const float*)d_in[5];
    const float* Wv  = (const float*)d_in[6];  const float* bv  = (const float*)d_in[7];
    const float* Wo  = (const float*)d_in[8];  const float* bo  = (const float*)d_in[9];
    const float* g1  = (const float*)d_in[10]; const float* b1  = (const float*)d_in[11];
    const float* W1f = (const float*)d_in[12]; const float* b1f = (const float*)d_in[13];
    const float* W2f = (const float*)d_in[14]; const float* b2f = (const float*)d_in[15];
    const float* g2  = (const float*)d_in[16]; const float* b2  = (const float*)d_in[17];
    const float* ng  = (const float*)d_in[18]; const float* nb  = (const float*)d_in[19];
    const float* lw  = (const float*)d_in[20]; const float* lb  = (const float*)d_in[21];
    float* out = (float*)d_out;

    char* ws = (char*)d_ws;
    const size_t MB = 1u << 20;
    const size_t SLOT = 48 * MB;               // 50,331,648 B (q16/k16/v16T exactly fit)
    int* fi = (int*)ws;                        // 65,280 B
    char* S1 = ws + MB;
    char* S2 = S1 + SLOT;
    char* S3 = S2 + SLOT;
    char* S4 = S3 + SLOT;                      // total 193 MiB (proven OK round 1/4)

    half_t* feat16 = (half_t*)S1;              // interleaved hi|lo, row = 1536 halves
    half_t* q16    = (half_t*)S2;              // [bh][256][192] -> ctx16 in-place
    half_t* k16    = (half_t*)S3;              // [bh][256][192]
    half_t* v16T   = (half_t*)S4;              // [bh][2][96][256]
    float*  t1     = (float*)S3;               // Wo out (k16 consumed)
    float*  xbuf   = (float*)S4;               // LN1 out (v16T consumed)
    half_t* x16    = (half_t*)S2;              // LN1 split out (ctx consumed by Wo)
    half_t* ffh_h  = (half_t*)S1;              // per-chunk hidden hi (feat16 consumed)
    half_t* ffh_l  = (half_t*)S3;              // per-chunk hidden lo (t1 consumed)
    float*  t2     = (float*)S2;               // overlays consumed x16 rows (3072 B stride)
    float*  x2     = (float*)S4;               // LN2 out (xbuf consumed)

    // weight prep (split-fp16, transposed, x64) into static device memory
    k_wsplit<<<dim3(24, 24), dim3(32, 8), 0, stream>>>(Wq, 768, 768, OFF_WQ_H, OFF_WQ_L);
    k_wsplit<<<dim3(24, 24), dim3(32, 8), 0, stream>>>(Wk, 768, 768, OFF_WK_H, OFF_WK_L);
    k_wsplit<<<dim3(24, 24), dim3(32, 8), 0, stream>>>(Wv, 768, 768, OFF_WV_H, OFF_WV_L);
    k_wsplit<<<dim3(24, 24), dim3(32, 8), 0, stream>>>(Wo, 768, 768, OFF_WO_H, OFF_WO_L);
    k_wsplit<<<dim3(96, 24), dim3(32, 8), 0, stream>>>(W1f, 768, 3072, OFF_W1_H, OFF_W1_L);
    k_wsplit<<<dim3(24, 96), dim3(32, 8), 0, stream>>>(W2f, 3072, 768, OFF_W2_H, OFF_W2_L);

    k_init_fi<<<(Bsz * Wn + 255) / 256, 256, 0, stream>>>(fi);
    k_scan<<<(Bsz * Tt) / 256, 256, 0, stream>>>(wid, fi);
    k_gather<<<(NROWS * 192 + 255) / 256, 256, 0, stream>>>((const float4*)ob, fi, feat16);

    // QKV GEMMs -> fp16 hi/lo head-major (Q,K) / transposed (V)
    dim3 gqkv(6, 128);
    k_gemm16<0, 0><<<gqkv, 256, 0, stream>>>(feat16, feat16 + 768, 1536, OFF_WQ_H, OFF_WQ_L,
                                             bq, nullptr, q16, nullptr, NROWS, Dd, Dd);
    k_gemm16<0, 0><<<gqkv, 256, 0, stream>>>(feat16, feat16 + 768, 1536, OFF_WK_H, OFF_WK_L,
                                             bk, nullptr, k16, nullptr, NROWS, Dd, Dd);
    k_gemm16<4, 0><<<gqkv, 256, 0, stream>>>(feat16, feat16 + 768, 1536, OFF_WV_H, OFF_WV_L,
                                             bv, nullptr, v16T, nullptr, NROWS, Dd, Dd);

    k_attn2<<<Bsz * Hh, 256, 0, stream>>>(q16, k16, v16T);    // ctx overwrites q16

    // t1 = feat + ctx@Wo + bo (AMODE 1 gathers head-major ctx) ; x = LN1(t1)
    k_gemm16<1, 1><<<gqkv, 256, 0, stream>>>(q16, q16 + 96, 0, OFF_WO_H, OFF_WO_L,
                                             bo, feat16, t1, nullptr, NROWS, Dd, Dd);
    k_ln<1><<<NROWS, 256, 0, stream>>>(t1, g1, b1, xbuf, x16);

    // FFN in 2 row-chunks of 8160
    for (int c = 0; c < 2; ++c) {
        const int r0 = c * 8160, mc = 8160;
        dim3 gf1(24, 64);
        k_gemm16<2, 0><<<gf1, 256, 0, stream>>>(x16 + (size_t)r0 * 1536, x16 + (size_t)r0 * 1536 + 768, 1536,
                                                OFF_W1_H, OFF_W1_L, b1f, nullptr,
                                                ffh_h, ffh_l, mc, 3072, Dd);
        dim3 gf2(6, 64);
        k_gemm16<3, 0><<<gf2, 256, 0, stream>>>(ffh_h, ffh_l, 3072,
                                                OFF_W2_H, OFF_W2_L, b2f, xbuf + (size_t)r0 * Dd,
                                                t2 + (size_t)r0 * Dd, nullptr, mc, Dd, 3072);
    }

    k_ln<0><<<NROWS, 256, 0, stream>>>(t2, g2, b2, x2, nullptr);
    k_final<<<NROWS, 256, 0, stream>>>(x2, ng, nb, lw, lb, out);
}

// Round 6
// 1347.888 us; speedup vs baseline: 3.0844x; 1.0027x over previous
//
#include <hip/hip_runtime.h>
#include <cmath>

#define Bsz 64
#define Tt  512
#define Dd  768
#define Wn  255
#define Hh  8
#define DHd 96
#define NROWS (Bsz*Wn)   // 16320

typedef _Float16 half_t;
typedef _Float16 f16x8 __attribute__((ext_vector_type(8)));
typedef _Float16 f16x4 __attribute__((ext_vector_type(4)));
typedef float f32x4 __attribute__((ext_vector_type(4)));

// ---- split-fp16 weights (transposed [N][K]), ~27 MiB static device memory ----
// scales: weights x64, activations x16, GEMM epilogue descales by 1/1024.
// QKV hi-planes contiguous (rows: Q 0-767, K 768-1535, V 1536-2303), then lo.
#define OFF_QKV_H 0
#define OFF_QKV_L 1769472
#define OFF_WO_H 3538944
#define OFF_WO_L 4128768
#define OFF_W1_H 4718592
#define OFF_W1_L 7077888
#define OFF_W2_H 9437184
#define OFF_W2_L 11796480
#define SLOTH 25165824        // halves per 48 MiB workspace slot (q16->k16->v16T)
__device__ __align__(16) half_t g_w16[14155776];

__device__ __forceinline__ void gload16(const half_t* g, half_t* l) {
    __builtin_amdgcn_global_load_lds((const __attribute__((address_space(1))) void*)g,
                                     (__attribute__((address_space(3))) void*)l, 16, 0, 0);
}

// ---------------- gather: first-subtoken index + feature copy ----------------

__global__ void k_init_fi(int* fi) {
    int i = blockIdx.x * 256 + threadIdx.x;
    if (i < Bsz * Wn) fi[i] = 0x7fffffff;
}

__global__ void k_scan(const int* __restrict__ wid, int* __restrict__ fi) {
    int i = blockIdx.x * 256 + threadIdx.x;   // over B*T
    if (i >= Bsz * Tt) return;
    int b = i / Tt, t = i % Tt;
    int w = wid[i];
    if (w >= 0 && w < Wn) atomicMin(&fi[b * Wn + w], t);
}

__global__ void k_bcat(const float* __restrict__ bq, const float* __restrict__ bk,
                       const float* __restrict__ bv, float* __restrict__ o) {
    int i = blockIdx.x * 256 + threadIdx.x;
    if (i < 768) o[i] = bq[i];
    else if (i < 1536) o[i] = bk[i - 768];
    else if (i < 2304) o[i] = bv[i - 1536];
}

// gather directly into interleaved fp16 hi/lo records (row = 1536 halves: hi[768]|lo[768])
__global__ void k_gather(const float4* __restrict__ ob, const int* __restrict__ fi,
                         half_t* __restrict__ f16) {
    int i = blockIdx.x * 256 + threadIdx.x;   // over NROWS*192
    if (i >= NROWS * 192) return;
    int r = i / 192, c = i % 192;
    int b = r / Wn;
    int idx = fi[r];
    if (idx == 0x7fffffff) idx = 0;           // argmax(all-False) == 0
    float4 v = ob[((size_t)b * Tt + idx) * 192 + c];
    float a0 = v.x * 16.f, a1 = v.y * 16.f, a2 = v.z * 16.f, a3 = v.w * 16.f;
    half_t h0 = (half_t)a0, h1 = (half_t)a1, h2 = (half_t)a2, h3 = (half_t)a3;
    f16x4 hv = {h0, h1, h2, h3};
    f16x4 lv = {(half_t)(a0 - (float)h0), (half_t)(a1 - (float)h1),
                (half_t)(a2 - (float)h2), (half_t)(a3 - (float)h3)};
    size_t off = (size_t)r * 1536 + c * 4;
    *(f16x4*)&f16[off] = hv;
    *(f16x4*)&f16[off + 768] = lv;
}

// ---------------- weight transpose + split: W[K,N] -> WT_h/WT_l [N,K] x64 ----

__global__ void k_wsplit(const float* __restrict__ Wm, int K, int N,
                         size_t off_h, size_t off_l) {
    __shared__ float sm[32][33];
    const int tx = threadIdx.x, ty = threadIdx.y;
    const int n0 = blockIdx.x * 32, k0 = blockIdx.y * 32;
    #pragma unroll
    for (int r = 0; r < 4; ++r)
        sm[ty + r * 8][tx] = Wm[(size_t)(k0 + ty + r * 8) * N + n0 + tx];
    __syncthreads();
    half_t* oh = g_w16 + off_h;
    half_t* ol = g_w16 + off_l;
    #pragma unroll
    for (int r = 0; r < 4; ++r) {
        float v = 64.f * sm[tx][ty + r * 8];
        half_t hi = (half_t)v;
        size_t o = (size_t)(n0 + ty + r * 8) * K + k0 + tx;
        oh[o] = hi;
        ol[o] = (half_t)(v - (float)hi);
    }
}

// ---------------- split-fp16 MFMA GEMM ---------------------------------------
// A: hi/lo fp16 (x16). AMODE 0: linear rows, stride lda halves.
//                      AMODE 1: head-major ctx [bh][256][hi96|lo96].
// B: g_w16+boff, [N][K] (x64). C_logical = acc/1024.
// NTILE: 128 (waves 2x2 of 64x64) or 64 (waves 4x1 of 32x64, 3 blocks/CU).
// MODE 5: fused QKV epilogue -> q16 / k16 (head-major) / v16T (transposed)
// MODE 1: fp32 row-major + interleaved fp16-pair residual (O-proj)
// MODE 2: relu -> fp16 hi/lo pair out x16 (FFN1)
// MODE 3: fp32 row-major + fp32 residual (FFN2)

template<int MODE, int AMODE, int NTILE>
__global__ __launch_bounds__(256, NTILE == 64 ? 3 : 2) void k_gemm16(
    const half_t* __restrict__ Ah, const half_t* __restrict__ Al, int lda,
    size_t boff_h, size_t boff_l,
    const float* __restrict__ bias,
    const void* __restrict__ res,
    void* __restrict__ out0, void* __restrict__ out1,
    int M, int N, int K) {
    constexpr int MI = (NTILE == 128 ? 4 : 2);
    __shared__ half_t sA[2][128 * 32];
    __shared__ half_t sB[2][NTILE * 32];
    const int tid = threadIdx.x;
    const int w = tid >> 6, l = tid & 63;
    const int row0 = blockIdx.y * 128, col0 = blockIdx.x * NTILE;
    const half_t* Bh = g_w16 + boff_h;
    const half_t* Bl = g_w16 + boff_l;

    const int srow = l >> 2;            // 0..15
    const int skk  = (l & 3) * 8;       // 0,8,16,24
    const int fr = l & 15, qk = (l >> 4) * 8;
    const int mh = (NTILE == 128) ? (w >> 1) * 64 : w * 32;
    const int nh = (NTILE == 128) ? (w & 1) * 64 : 0;

    f32x4 acc[MI][4];
    #pragma unroll
    for (int i = 0; i < MI; ++i)
        #pragma unroll
        for (int j = 0; j < 4; ++j) acc[i][j] = (f32x4){0.f, 0.f, 0.f, 0.f};

    for (int k0 = 0; k0 < K; k0 += 32) {
        #pragma unroll
        for (int t = 0; t < 2; ++t) {
            int r = (w * 2 + t) * 16 + srow;
            int grA = row0 + r; if (grA >= M) grA = M - 1;
            half_t* da  = (half_t*)&sA[0][(w * 2 + t) * 512];
            half_t* da2 = (half_t*)&sA[1][(w * 2 + t) * 512];
            if (AMODE == 1) {
                int b = grA / 255, wl = grA - b * 255;
                int kk = k0 + skk;
                int h = kk / 96, d = kk - h * 96;
                size_t aoff = ((size_t)(b * 8 + h) * 256 + wl) * 192 + d;
                gload16(Ah + aoff, da);
                gload16(Al + aoff, da2);
            } else {
                gload16(Ah + (size_t)grA * lda + k0 + skk, da);
                gload16(Al + (size_t)grA * lda + k0 + skk, da2);
            }
            if (NTILE == 128 || t == 0) {
                int bs = (NTILE == 128) ? (w * 2 + t) : w;
                int grB = col0 + bs * 16 + srow;
                gload16(Bh + (size_t)grB * K + k0 + skk, (half_t*)&sB[0][bs * 512]);
                gload16(Bl + (size_t)grB * K + k0 + skk, (half_t*)&sB[1][bs * 512]);
            }
        }
        __syncthreads();
        f16x8 a0[MI], a1[MI], b0[4], b1[4];
        #pragma unroll
        for (int i = 0; i < MI; ++i) {
            a0[i] = *(const f16x8*)&sA[0][(mh + i * 16 + fr) * 32 + qk];
            a1[i] = *(const f16x8*)&sA[1][(mh + i * 16 + fr) * 32 + qk];
        }
        #pragma unroll
        for (int j = 0; j < 4; ++j) {
            b0[j] = *(const f16x8*)&sB[0][(nh + j * 16 + fr) * 32 + qk];
            b1[j] = *(const f16x8*)&sB[1][(nh + j * 16 + fr) * 32 + qk];
        }
        #pragma unroll
        for (int i = 0; i < MI; ++i)
            #pragma unroll
            for (int j = 0; j < 4; ++j) {
                acc[i][j] = __builtin_amdgcn_mfma_f32_16x16x32_f16(a0[i], b0[j], acc[i][j], 0, 0, 0);
                acc[i][j] = __builtin_amdgcn_mfma_f32_16x16x32_f16(a0[i], b1[j], acc[i][j], 0, 0, 0);
                acc[i][j] = __builtin_amdgcn_mfma_f32_16x16x32_f16(a1[i], b0[j], acc[i][j], 0, 0, 0);
            }
        __syncthreads();
    }

    const float dsc = 1.0f / 1024.0f;
    #pragma unroll
    for (int i = 0; i < MI; ++i) {
        #pragma unroll
        for (int r = 0; r < 4; ++r) {
            int row = row0 + mh + i * 16 + ((l >> 4) << 2) + r;
            if (row >= M) continue;
            #pragma unroll
            for (int j = 0; j < 4; ++j) {
                int col = col0 + nh + j * 16 + (l & 15);
                float vv = acc[i][j][r] * dsc + bias[col];
                if (MODE == 5) {
                    int b = row / 255, wl = row - b * 255;
                    float t16 = vv * 16.f;
                    half_t hi = (half_t)t16;
                    half_t lo = (half_t)(t16 - (float)hi);
                    half_t* o0 = (half_t*)out0;
                    if (col < 1536) {
                        int cc = (col < 768) ? col : col - 768;
                        half_t* dst = o0 + ((col < 768) ? 0 : (size_t)SLOTH);
                        int h = cc / 96, d = cc - h * 96;
                        size_t o = ((size_t)(b * 8 + h) * 256 + wl) * 192 + d;
                        dst[o] = hi; dst[o + 96] = lo;
                    } else {
                        int cc = col - 1536;
                        int h = cc / 96, d = cc - h * 96;
                        half_t* dst = o0 + 2 * (size_t)SLOTH;
                        size_t o = (size_t)(b * 8 + h) * 49152 + (size_t)d * 256 + wl;
                        dst[o] = hi; dst[o + 24576] = lo;
                    }
                } else if (MODE == 1) {
                    const half_t* rp = (const half_t*)res;
                    vv += ((float)rp[(size_t)row * 1536 + col] +
                           (float)rp[(size_t)row * 1536 + 768 + col]) * 0.0625f;
                    ((float*)out0)[(size_t)row * N + col] = vv;
                } else if (MODE == 2) {
                    vv = fmaxf(vv, 0.f);
                    float t16 = vv * 16.f;
                    half_t hi = (half_t)t16;
                    ((half_t*)out0)[(size_t)row * N + col] = hi;
                    ((half_t*)out1)[(size_t)row * N + col] = (half_t)(t16 - (float)hi);
                } else {
                    vv += ((const float*)res)[(size_t)row * N + col];
                    ((float*)out0)[(size_t)row * N + col] = vv;
                }
            }
        }
    }
}

// ---------------- flash MFMA attention, split-fp16, one block per (b,h) ------
// q/ctx: [bh][256][hi96|lo96] x16; k same; vT: [bh][2][96][256] x16.
// ctx overwrites q in-place (per-wave rows, read-before-write within tile).

__global__ __launch_bounds__(256, 2) void k_attn2(half_t* __restrict__ qc,
                                                  const half_t* __restrict__ kk16,
                                                  const half_t* __restrict__ vt16) {
    __shared__ half_t sK[64][200];      // [key][hi96|lo96], pad 200
    __shared__ half_t sVT[192][72];     // [(plane*96+dim)][key64], pad 72
    __shared__ float  sP[4][16][68];    // per-wave P [qrow][key], pad 68
    const int tid = threadIdx.x;
    const int w = tid >> 6, l = tid & 63;
    const int lr = l & 15, lc = l >> 4;
    const size_t base = (size_t)blockIdx.x * 49152;
    const float ssc = 0.10206207261596575f / 256.0f;   // 1/sqrt(96) / (16*16)

    for (int qt = 0; qt < 4; ++qt) {
        const int qrow0 = qt * 64 + w * 16;
        f16x8 qf[2][3];
        #pragma unroll
        for (int p = 0; p < 2; ++p)
            #pragma unroll
            for (int s = 0; s < 3; ++s)
                qf[p][s] = *(const f16x8*)(qc + base + (size_t)(qrow0 + lr) * 192
                                           + p * 96 + s * 32 + lc * 8);
        f32x4 O[6];
        #pragma unroll
        for (int dn = 0; dn < 6; ++dn) O[dn] = (f32x4){0.f, 0.f, 0.f, 0.f};
        float mrow[4] = {-3e38f, -3e38f, -3e38f, -3e38f};
        float lrow[4] = {0.f, 0.f, 0.f, 0.f};

        for (int kt = 0; kt < 4; ++kt) {
            __syncthreads();
            #pragma unroll
            for (int c = 0; c < 6; ++c) {
                int ch = w + c * 4;
                *(f16x8*)&sK[l][ch * 8] =
                    *(const f16x8*)(kk16 + base + (size_t)(kt * 64 + l) * 192 + ch * 8);
            }
            #pragma unroll
            for (int c = 0; c < 6; ++c) {
                int u = c * 256 + tid;
                int pd = u >> 3, ch = u & 7;
                *(f16x8*)&sVT[pd][ch * 8] =
                    *(const f16x8*)(vt16 + base + (size_t)pd * 256 + kt * 64 + ch * 8);
            }
            __syncthreads();
            f32x4 sacc[4];
            #pragma unroll
            for (int nt = 0; nt < 4; ++nt) sacc[nt] = (f32x4){0.f, 0.f, 0.f, 0.f};
            #pragma unroll
            for (int s = 0; s < 3; ++s)
                #pragma unroll
                for (int nt = 0; nt < 4; ++nt) {
                    f16x8 kh = *(const f16x8*)&sK[nt * 16 + lr][s * 32 + lc * 8];
                    f16x8 klo = *(const f16x8*)&sK[nt * 16 + lr][96 + s * 32 + lc * 8];
                    sacc[nt] = __builtin_amdgcn_mfma_f32_16x16x32_f16(qf[0][s], kh, sacc[nt], 0, 0, 0);
                    sacc[nt] = __builtin_amdgcn_mfma_f32_16x16x32_f16(qf[0][s], klo, sacc[nt], 0, 0, 0);
                    sacc[nt] = __builtin_amdgcn_mfma_f32_16x16x32_f16(qf[1][s], kh, sacc[nt], 0, 0, 0);
                }
            float sv[4][4], mx[4] = {-3e38f, -3e38f, -3e38f, -3e38f};
            #pragma unroll
            for (int nt = 0; nt < 4; ++nt) {
                int key = kt * 64 + nt * 16 + lr;
                #pragma unroll
                for (int r = 0; r < 4; ++r) {
                    float s_ = sacc[nt][r] * ssc;
                    if (key >= 255) s_ = -3e38f;
                    sv[nt][r] = s_;
                    mx[r] = fmaxf(mx[r], s_);
                }
            }
            #pragma unroll
            for (int r = 0; r < 4; ++r) {
                mx[r] = fmaxf(mx[r], __shfl_xor(mx[r], 1));
                mx[r] = fmaxf(mx[r], __shfl_xor(mx[r], 2));
                mx[r] = fmaxf(mx[r], __shfl_xor(mx[r], 4));
                mx[r] = fmaxf(mx[r], __shfl_xor(mx[r], 8));
            }
            float alpha[4], rs[4];
            #pragma unroll
            for (int r = 0; r < 4; ++r) {
                float mn = fmaxf(mrow[r], mx[r]);
                alpha[r] = __expf(mrow[r] - mn);
                mrow[r] = mn;
                rs[r] = 0.f;
            }
            float pv[4][4];
            #pragma unroll
            for (int nt = 0; nt < 4; ++nt)
                #pragma unroll
                for (int r = 0; r < 4; ++r) {
                    float p = __expf(sv[nt][r] - mrow[r]);
                    pv[nt][r] = p;
                    rs[r] += p;
                }
            #pragma unroll
            for (int r = 0; r < 4; ++r) {
                rs[r] += __shfl_xor(rs[r], 1);
                rs[r] += __shfl_xor(rs[r], 2);
                rs[r] += __shfl_xor(rs[r], 4);
                rs[r] += __shfl_xor(rs[r], 8);
                lrow[r] = lrow[r] * alpha[r] + rs[r];
            }
            #pragma unroll
            for (int dn = 0; dn < 6; ++dn)
                #pragma unroll
                for (int r = 0; r < 4; ++r) O[dn][r] *= alpha[r];
            #pragma unroll
            for (int nt = 0; nt < 4; ++nt)
                #pragma unroll
                for (int r = 0; r < 4; ++r)
                    sP[w][lc * 4 + r][nt * 16 + lr] = pv[nt][r];
            #pragma unroll
            for (int ks = 0; ks < 2; ++ks) {
                const float* pp = &sP[w][lr][ks * 32 + lc * 8];
                f16x8 ph, pl;
                #pragma unroll
                for (int j = 0; j < 8; ++j) {
                    float p = pp[j];
                    half_t h_ = (half_t)p;
                    ph[j] = h_;
                    pl[j] = (half_t)(p - (float)h_);
                }
                #pragma unroll
                for (int dn = 0; dn < 6; ++dn) {
                    f16x8 vh = *(const f16x8*)&sVT[dn * 16 + lr][ks * 32 + lc * 8];
                    f16x8 vl = *(const f16x8*)&sVT[96 + dn * 16 + lr][ks * 32 + lc * 8];
                    O[dn] = __builtin_amdgcn_mfma_f32_16x16x32_f16(ph, vh, O[dn], 0, 0, 0);
                    O[dn] = __builtin_amdgcn_mfma_f32_16x16x32_f16(ph, vl, O[dn], 0, 0, 0);
                    O[dn] = __builtin_amdgcn_mfma_f32_16x16x32_f16(pl, vh, O[dn], 0, 0, 0);
                }
            }
        }
        #pragma unroll
        for (int r = 0; r < 4; ++r) {
            int qrow = qrow0 + lc * 4 + r;
            if (qrow >= Wn) continue;
            float inv = 1.0f / lrow[r];
            #pragma unroll
            for (int dn = 0; dn < 6; ++dn) {
                float val = O[dn][r] * inv;
                half_t hi = (half_t)val;
                half_t lo = (half_t)(val - (float)hi);
                size_t o = base + (size_t)qrow * 192 + dn * 16 + lr;
                qc[o] = hi;
                qc[o + 96] = lo;
            }
        }
    }
}

// ---------------- row LayerNorm (optional fused fp16-pair split output) -----

template<int SPLIT>
__global__ __launch_bounds__(256) void k_ln(const float* __restrict__ X, const float* __restrict__ g,
                                            const float* __restrict__ bt, float* __restrict__ Y,
                                            half_t* __restrict__ Y16) {
    const int r = blockIdx.x, tid = threadIdx.x;
    __shared__ float red[256];
    const float* x = X + (size_t)r * Dd;
    float x0 = x[tid], x1 = x[tid + 256], x2 = x[tid + 512];
    red[tid] = x0 + x1 + x2; __syncthreads();
    for (int s = 128; s > 0; s >>= 1) { if (tid < s) red[tid] += red[tid + s]; __syncthreads(); }
    float mean = red[0] * (1.0f / 768.0f);
    __syncthreads();
    float d0 = x0 - mean, d1 = x1 - mean, d2 = x2 - mean;
    red[tid] = d0 * d0 + d1 * d1 + d2 * d2; __syncthreads();
    for (int s = 128; s > 0; s >>= 1) { if (tid < s) red[tid] += red[tid + s]; __syncthreads(); }
    float rs = rsqrtf(red[0] * (1.0f / 768.0f) + 1e-5f);
    float* y = Y + (size_t)r * Dd;
    float y0 = d0 * rs * g[tid]       + bt[tid];
    float y1 = d1 * rs * g[tid + 256] + bt[tid + 256];
    float y2 = d2 * rs * g[tid + 512] + bt[tid + 512];
    y[tid] = y0; y[tid + 256] = y1; y[tid + 512] = y2;
    if (SPLIT) {
        half_t* h = Y16 + (size_t)r * 1536;
        float t0 = y0 * 16.f, t1 = y1 * 16.f, t2 = y2 * 16.f;
        half_t h0 = (half_t)t0, h1 = (half_t)t1, h2 = (half_t)t2;
        h[tid] = h0; h[tid + 256] = h1; h[tid + 512] = h2;
        h[768 + tid] = (half_t)(t0 - (float)h0);
        h[768 + tid + 256] = (half_t)(t1 - (float)h1);
        h[768 + tid + 512] = (half_t)(t2 - (float)h2);
    }
}

// ---------------- final LN + 2-class linear + softmax + argmax --------------

__global__ __launch_bounds__(256) void k_final(const float* __restrict__ X, const float* __restrict__ g,
                                               const float* __restrict__ bt, const float* __restrict__ lw,
                                               const float* __restrict__ lb, float* __restrict__ out) {
    const int r = blockIdx.x, tid = threadIdx.x;
    __shared__ float red[256];
    const float* x = X + (size_t)r * Dd;
    float x0 = x[tid], x1 = x[tid + 256], x2 = x[tid + 512];
    red[tid] = x0 + x1 + x2; __syncthreads();
    for (int s = 128; s > 0; s >>= 1) { if (tid < s) red[tid] += red[tid + s]; __syncthreads(); }
    float mean = red[0] * (1.0f / 768.0f);
    __syncthreads();
    float d0 = x0 - mean, d1 = x1 - mean, d2 = x2 - mean;
    red[tid] = d0 * d0 + d1 * d1 + d2 * d2; __syncthreads();
    for (int s = 128; s > 0; s >>= 1) { if (tid < s) red[tid] += red[tid + s]; __syncthreads(); }
    float rs = rsqrtf(red[0] * (1.0f / 768.0f) + 1e-5f);
    __syncthreads();
    float n0 = d0 * rs * g[tid]       + bt[tid];
    float n1 = d1 * rs * g[tid + 256] + bt[tid + 256];
    float n2 = d2 * rs * g[tid + 512] + bt[tid + 512];
    float l0 = n0 * lw[2 * tid]     + n1 * lw[2 * (tid + 256)]     + n2 * lw[2 * (tid + 512)];
    float l1 = n0 * lw[2 * tid + 1] + n1 * lw[2 * (tid + 256) + 1] + n2 * lw[2 * (tid + 512) + 1];
    red[tid] = l0; __syncthreads();
    for (int s = 128; s > 0; s >>= 1) { if (tid < s) red[tid] += red[tid + s]; __syncthreads(); }
    l0 = red[0]; __syncthreads();
    red[tid] = l1; __syncthreads();
    for (int s = 128; s > 0; s >>= 1) { if (tid < s) red[tid] += red[tid + s]; __syncthreads(); }
    l1 = red[0];
    if (tid == 0) {
        l0 += lb[0]; l1 += lb[1];
        float m = fmaxf(l0, l1);
        float e0 = expf(l0 - m), e1 = expf(l1 - m);
        float inv = 1.0f / (e0 + e1);
        out[2 * r] = e0 * inv;
        out[2 * r + 1] = e1 * inv;
        out[2 * NROWS + r] = (l1 > l0) ? 1.0f : 0.0f;   // tie -> first index (0)
    }
}

// ---------------- launch --------------------------------------------------

extern "C" void kernel_launch(void* const* d_in, const int* in_sizes, int n_in,
                              void* d_out, int out_size, void* d_ws, size_t ws_size,
                              hipStream_t stream) {
    const float* ob  = (const float*)d_in[0];
    const int*   wid = (const int*)d_in[1];
    const float* Wq  = (const float*)d_in[2];  const float* bq  = (const float*)d_in[3];
    const float* Wk  = (const float*)d_in[4];  const float* bk  = (const float*)d_in[5];
    const float* Wv  = (const float*)d_in[6];  const float* bv  = (const float*)d_in[7];
    const float* Wo  = (const float*)d_in[8];  const float* bo  = (const float*)d_in[9];
    const float* g1  = (const float*)d_in[10]; const float* b1  = (const float*)d_in[11];
    const float* W1f = (const float*)d_in[12]; const float* b1f = (const float*)d_in[13];
    const float* W2f = (const float*)d_in[14]; const float* b2f = (const float*)d_in[15];
    const float* g2  = (const float*)d_in[16]; const float* b2  = (const float*)d_in[17];
    const float* ng  = (const float*)d_in[18]; const float* nb  = (const float*)d_in[19];
    const float* lw  = (const float*)d_in[20]; const float* lb  = (const float*)d_in[21];
    float* out = (float*)d_out;

    char* ws = (char*)d_ws;
    const size_t MB = 1u << 20;
    const size_t SLOT = 48 * MB;               // 50,331,648 B; SLOTH = SLOT/2 halves
    int* fi = (int*)ws;                        // 65,280 B
    float* bcat = (float*)(ws + 262144);       // 2304 floats
    char* S1 = ws + MB;
    char* S2 = S1 + SLOT;
    char* S3 = S2 + SLOT;
    char* S4 = S3 + SLOT;                      // total 193 MiB (proven OK)

    half_t* feat16 = (half_t*)S1;              // interleaved hi|lo, row = 1536 halves
    half_t* q16    = (half_t*)S2;              // [bh][256][192] -> ctx16 in-place
    half_t* k16    = (half_t*)S3;              // [bh][256][192]  (= q16 + SLOTH)
    half_t* v16T   = (half_t*)S4;              // [bh][2][96][256] (= q16 + 2*SLOTH)
    float*  t1     = (float*)S3;               // Wo out (k16 consumed)
    float*  xbuf   = (float*)S4;               // LN1 out (v16T consumed)
    half_t* x16    = (half_t*)S2;              // LN1 split out (ctx consumed by Wo)
    half_t* ffh_h  = (half_t*)S1;              // per-chunk hidden hi (feat16 consumed)
    half_t* ffh_l  = (half_t*)S3;              // per-chunk hidden lo (t1 consumed)
    float*  t2     = (float*)S2;               // overlays consumed x16 rows (3072 B stride)
    float*  x2     = (float*)S4;               // LN2 out (xbuf consumed)

    // weight prep: QKV hi contiguous [0,1769472), QKV lo [1769472,3538944)
    k_wsplit<<<dim3(24, 24), dim3(32, 8), 0, stream>>>(Wq, 768, 768, 0, 1769472);
    k_wsplit<<<dim3(24, 24), dim3(32, 8), 0, stream>>>(Wk, 768, 768, 589824, 2359296);
    k_wsplit<<<dim3(24, 24), dim3(32, 8), 0, stream>>>(Wv, 768, 768, 1179648, 2949120);
    k_wsplit<<<dim3(24, 24), dim3(32, 8), 0, stream>>>(Wo, 768, 768, OFF_WO_H, OFF_WO_L);
    k_wsplit<<<dim3(96, 24), dim3(32, 8), 0, stream>>>(W1f, 768, 3072, OFF_W1_H, OFF_W1_L);
    k_wsplit<<<dim3(24, 96), dim3(32, 8), 0, stream>>>(W2f, 3072, 768, OFF_W2_H, OFF_W2_L);
    k_bcat<<<9, 256, 0, stream>>>(bq, bk, bv, bcat);

    k_init_fi<<<(Bsz * Wn + 255) / 256, 256, 0, stream>>>(fi);
    k_scan<<<(Bsz * Tt) / 256, 256, 0, stream>>>(wid, fi);
    k_gather<<<(NROWS * 192 + 255) / 256, 256, 0, stream>>>((const float4*)ob, fi, feat16);

    // fused QKV GEMM -> q16 / k16 / v16T (2304 blocks = 9/CU)
    k_gemm16<5, 0, 128><<<dim3(18, 128), 256, 0, stream>>>(
        feat16, feat16 + 768, 1536, OFF_QKV_H, OFF_QKV_L,
        bcat, nullptr, q16, nullptr, NROWS, 2304, Dd);

    k_attn2<<<Bsz * Hh, 256, 0, stream>>>(q16, k16, v16T);    // ctx overwrites q16

    // t1 = feat + ctx@Wo + bo (AMODE 1 gathers head-major ctx) ; x = LN1(t1)
    k_gemm16<1, 1, 128><<<dim3(6, 128), 256, 0, stream>>>(
        q16, q16 + 96, 0, OFF_WO_H, OFF_WO_L,
        bo, feat16, t1, nullptr, NROWS, Dd, Dd);
    k_ln<1><<<NROWS, 256, 0, stream>>>(t1, g1, b1, xbuf, x16);

    // FFN in 2 row-chunks of 8160; FFN2 uses 64-wide N tiles (768 blocks = 3/CU)
    for (int c = 0; c < 2; ++c) {
        const int r0 = c * 8160, mc = 8160;
        k_gemm16<2, 0, 128><<<dim3(24, 64), 256, 0, stream>>>(
            x16 + (size_t)r0 * 1536, x16 + (size_t)r0 * 1536 + 768, 1536,
            OFF_W1_H, OFF_W1_L, b1f, nullptr, ffh_h, ffh_l, mc, 3072, Dd);
        k_gemm16<3, 0, 64><<<dim3(12, 64), 256, 0, stream>>>(
            ffh_h, ffh_l, 3072, OFF_W2_H, OFF_W2_L, b2f, xbuf + (size_t)r0 * Dd,
            t2 + (size_t)r0 * Dd, nullptr, mc, Dd, 3072);
    }

    k_ln<0><<<NROWS, 256, 0, stream>>>(t2, g2, b2, x2, nullptr);
    k_final<<<NROWS, 256, 0, stream>>>(x2, ng, nb, lw, lb, out);
}

// Round 7
// 1157.099 us; speedup vs baseline: 3.5930x; 1.1649x over previous
//
#include <hip/hip_runtime.h>
#include <cmath>

#define Bsz 64
#define Tt  512
#define Dd  768
#define Wn  255
#define Hh  8
#define DHd 96
#define NROWS (Bsz*Wn)   // 16320

typedef _Float16 half_t;
typedef _Float16 f16x8 __attribute__((ext_vector_type(8)));
typedef _Float16 f16x4 __attribute__((ext_vector_type(4)));
typedef float f32x4 __attribute__((ext_vector_type(4)));

// ---- split-fp16 weights (transposed [N][K]), ~27 MiB static device memory ----
// scales: weights x64, activations x16, GEMM epilogue descales by 1/1024.
// QKV hi-planes contiguous (rows: Q 0-767, K 768-1535, V 1536-2303), then lo.
#define OFF_QKV_H 0
#define OFF_QKV_L 1769472
#define OFF_WO_H 3538944
#define OFF_WO_L 4128768
#define OFF_W1_H 4718592
#define OFF_W1_L 7077888
#define OFF_W2_H 9437184
#define OFF_W2_L 11796480
#define SLOTH 25165824        // halves per 48 MiB workspace slot (q16->k16->v16)
__device__ __align__(16) half_t g_w16[14155776];

__device__ __forceinline__ void gload16(const half_t* g, half_t* l) {
    __builtin_amdgcn_global_load_lds((const __attribute__((address_space(1))) void*)g,
                                     (__attribute__((address_space(3))) void*)l, 16, 0, 0);
}

// ---------------- gather: first-subtoken index + feature copy ----------------

__global__ void k_init_fi(int* fi) {
    int i = blockIdx.x * 256 + threadIdx.x;
    if (i < Bsz * Wn) fi[i] = 0x7fffffff;
}

__global__ void k_scan(const int* __restrict__ wid, int* __restrict__ fi) {
    int i = blockIdx.x * 256 + threadIdx.x;   // over B*T
    if (i >= Bsz * Tt) return;
    int b = i / Tt, t = i % Tt;
    int w = wid[i];
    if (w >= 0 && w < Wn) atomicMin(&fi[b * Wn + w], t);
}

__global__ void k_bcat(const float* __restrict__ bq, const float* __restrict__ bk,
                       const float* __restrict__ bv, float* __restrict__ o) {
    int i = blockIdx.x * 256 + threadIdx.x;
    if (i < 768) o[i] = bq[i];
    else if (i < 1536) o[i] = bk[i - 768];
    else if (i < 2304) o[i] = bv[i - 1536];
}

// gather directly into interleaved fp16 hi/lo records (row = 1536 halves: hi[768]|lo[768])
__global__ void k_gather(const float4* __restrict__ ob, const int* __restrict__ fi,
                         half_t* __restrict__ f16) {
    int i = blockIdx.x * 256 + threadIdx.x;   // over NROWS*192
    if (i >= NROWS * 192) return;
    int r = i / 192, c = i % 192;
    int b = r / Wn;
    int idx = fi[r];
    if (idx == 0x7fffffff) idx = 0;           // argmax(all-False) == 0
    float4 v = ob[((size_t)b * Tt + idx) * 192 + c];
    float a0 = v.x * 16.f, a1 = v.y * 16.f, a2 = v.z * 16.f, a3 = v.w * 16.f;
    half_t h0 = (half_t)a0, h1 = (half_t)a1, h2 = (half_t)a2, h3 = (half_t)a3;
    f16x4 hv = {h0, h1, h2, h3};
    f16x4 lv = {(half_t)(a0 - (float)h0), (half_t)(a1 - (float)h1),
                (half_t)(a2 - (float)h2), (half_t)(a3 - (float)h3)};
    size_t off = (size_t)r * 1536 + c * 4;
    *(f16x4*)&f16[off] = hv;
    *(f16x4*)&f16[off + 768] = lv;
}

// ---------------- weight transpose + split: W[K,N] -> WT_h/WT_l [N,K] x64 ----

__global__ void k_wsplit(const float* __restrict__ Wm, int K, int N,
                         size_t off_h, size_t off_l) {
    __shared__ float sm[32][33];
    const int tx = threadIdx.x, ty = threadIdx.y;
    const int n0 = blockIdx.x * 32, k0 = blockIdx.y * 32;
    #pragma unroll
    for (int r = 0; r < 4; ++r)
        sm[ty + r * 8][tx] = Wm[(size_t)(k0 + ty + r * 8) * N + n0 + tx];
    __syncthreads();
    half_t* oh = g_w16 + off_h;
    half_t* ol = g_w16 + off_l;
    #pragma unroll
    for (int r = 0; r < 4; ++r) {
        float v = 64.f * sm[tx][ty + r * 8];
        half_t hi = (half_t)v;
        size_t o = (size_t)(n0 + ty + r * 8) * K + k0 + tx;
        oh[o] = hi;
        ol[o] = (half_t)(v - (float)hi);
    }
}

// ---------------- split-fp16 MFMA GEMM ---------------------------------------
// A: hi/lo fp16 (x16). AMODE 0: linear rows, stride lda halves.
//                      AMODE 1: head-major ctx [bh][256][hi96|lo96].
// B: g_w16+boff, [N][K] (x64). C_logical = acc/1024.
// Grid swizzle: xcd = lin&7 gets contiguous row-tiles (needs gridDim.y%8==0)
// so A row-tiles stay L2-resident per XCD (round-robin dispatch heuristic).
// MODE 5: fused QKV -> q16/k16/v16 all head-major [bh][256][hi96|lo96]
// MODE 1: fp32 row-major + interleaved fp16-pair residual (O-proj)
// MODE 2: relu -> fp16 hi/lo pair out x16 (FFN1)
// MODE 3: fp32 row-major + fp32 residual (FFN2)

template<int MODE, int AMODE, int NTILE>
__global__ __launch_bounds__(256, NTILE == 64 ? 3 : 2) void k_gemm16(
    const half_t* __restrict__ Ah, const half_t* __restrict__ Al, int lda,
    size_t boff_h, size_t boff_l,
    const float* __restrict__ bias,
    const void* __restrict__ res,
    void* __restrict__ out0, void* __restrict__ out1,
    int M, int N, int K) {
    constexpr int MI = (NTILE == 128 ? 4 : 2);
    __shared__ half_t sA[2][128 * 32];
    __shared__ half_t sB[2][NTILE * 32];
    const int tid = threadIdx.x;
    const int w = tid >> 6, l = tid & 63;
    // XCD-locality swizzle
    int lin = blockIdx.y * gridDim.x + blockIdx.x;
    int rpx = gridDim.y >> 3;                    // row-tiles per XCD
    int j_ = lin >> 3;
    int jr = j_ / gridDim.x;
    int by = (lin & 7) * rpx + jr;
    int bx = j_ - jr * gridDim.x;
    const int row0 = by * 128, col0 = bx * NTILE;
    const half_t* Bh = g_w16 + boff_h;
    const half_t* Bl = g_w16 + boff_l;

    const int srow = l >> 2;            // 0..15
    const int skk  = (l & 3) * 8;       // 0,8,16,24
    const int fr = l & 15, qk = (l >> 4) * 8;
    const int mh = (NTILE == 128) ? (w >> 1) * 64 : w * 32;
    const int nh = (NTILE == 128) ? (w & 1) * 64 : 0;

    f32x4 acc[MI][4];
    #pragma unroll
    for (int i = 0; i < MI; ++i)
        #pragma unroll
        for (int j = 0; j < 4; ++j) acc[i][j] = (f32x4){0.f, 0.f, 0.f, 0.f};

    for (int k0 = 0; k0 < K; k0 += 32) {
        #pragma unroll
        for (int t = 0; t < 2; ++t) {
            int r = (w * 2 + t) * 16 + srow;
            int grA = row0 + r; if (grA >= M) grA = M - 1;
            half_t* da  = (half_t*)&sA[0][(w * 2 + t) * 512];
            half_t* da2 = (half_t*)&sA[1][(w * 2 + t) * 512];
            if (AMODE == 1) {
                int b = grA / 255, wl = grA - b * 255;
                int kk = k0 + skk;
                int h = kk / 96, d = kk - h * 96;
                size_t aoff = ((size_t)(b * 8 + h) * 256 + wl) * 192 + d;
                gload16(Ah + aoff, da);
                gload16(Al + aoff, da2);
            } else {
                gload16(Ah + (size_t)grA * lda + k0 + skk, da);
                gload16(Al + (size_t)grA * lda + k0 + skk, da2);
            }
            if (NTILE == 128 || t == 0) {
                int bs = (NTILE == 128) ? (w * 2 + t) : w;
                int grB = col0 + bs * 16 + srow;
                gload16(Bh + (size_t)grB * K + k0 + skk, (half_t*)&sB[0][bs * 512]);
                gload16(Bl + (size_t)grB * K + k0 + skk, (half_t*)&sB[1][bs * 512]);
            }
        }
        __syncthreads();
        f16x8 a0[MI], a1[MI], b0[4], b1[4];
        #pragma unroll
        for (int i = 0; i < MI; ++i) {
            a0[i] = *(const f16x8*)&sA[0][(mh + i * 16 + fr) * 32 + qk];
            a1[i] = *(const f16x8*)&sA[1][(mh + i * 16 + fr) * 32 + qk];
        }
        #pragma unroll
        for (int j = 0; j < 4; ++j) {
            b0[j] = *(const f16x8*)&sB[0][(nh + j * 16 + fr) * 32 + qk];
            b1[j] = *(const f16x8*)&sB[1][(nh + j * 16 + fr) * 32 + qk];
        }
        #pragma unroll
        for (int i = 0; i < MI; ++i)
            #pragma unroll
            for (int j = 0; j < 4; ++j) {
                acc[i][j] = __builtin_amdgcn_mfma_f32_16x16x32_f16(a0[i], b0[j], acc[i][j], 0, 0, 0);
                acc[i][j] = __builtin_amdgcn_mfma_f32_16x16x32_f16(a0[i], b1[j], acc[i][j], 0, 0, 0);
                acc[i][j] = __builtin_amdgcn_mfma_f32_16x16x32_f16(a1[i], b0[j], acc[i][j], 0, 0, 0);
            }
        __syncthreads();
    }

    const float dsc = 1.0f / 1024.0f;
    #pragma unroll
    for (int i = 0; i < MI; ++i) {
        #pragma unroll
        for (int r = 0; r < 4; ++r) {
            int row = row0 + mh + i * 16 + ((l >> 4) << 2) + r;
            if (row >= M) continue;
            #pragma unroll
            for (int j = 0; j < 4; ++j) {
                int col = col0 + nh + j * 16 + (l & 15);
                float vv = acc[i][j][r] * dsc + bias[col];
                if (MODE == 5) {
                    int b = row / 255, wl = row - b * 255;
                    int part = col / 768;              // 0=Q,1=K,2=V
                    int cc = col - part * 768;
                    int h = cc / 96, d = cc - h * 96;
                    float t16 = vv * 16.f;
                    half_t hi = (half_t)t16;
                    half_t lo = (half_t)(t16 - (float)hi);
                    half_t* dst = (half_t*)out0 + (size_t)part * SLOTH;
                    size_t o = ((size_t)(b * 8 + h) * 256 + wl) * 192 + d;
                    dst[o] = hi; dst[o + 96] = lo;
                } else if (MODE == 1) {
                    const half_t* rp = (const half_t*)res;
                    vv += ((float)rp[(size_t)row * 1536 + col] +
                           (float)rp[(size_t)row * 1536 + 768 + col]) * 0.0625f;
                    ((float*)out0)[(size_t)row * N + col] = vv;
                } else if (MODE == 2) {
                    vv = fmaxf(vv, 0.f);
                    float t16 = vv * 16.f;
                    half_t hi = (half_t)t16;
                    ((half_t*)out0)[(size_t)row * N + col] = hi;
                    ((half_t*)out1)[(size_t)row * N + col] = (half_t)(t16 - (float)hi);
                } else {
                    vv += ((const float*)res)[(size_t)row * N + col];
                    ((float*)out0)[(size_t)row * N + col] = vv;
                }
            }
        }
    }
}

// ---------------- flash MFMA attention, split-fp16, one block per (b,h) ------
// q/ctx/k/v all: [bh][256][hi96|lo96] x16. V transposed to [dim][key] in LDS
// at staging time (lanes along key -> 2-way bank aliasing, free).
// kt-outer / qt-inner in 2 passes: K/V staged 8x total (was 16x), O/m/l for
// 2 q-tiles held in registers. ctx overwrites q in-place after each pass
// (pass writes rows its own pass read; pass-1 reads rows 128+ only).

__global__ __launch_bounds__(256, 2) void k_attn2(half_t* __restrict__ qc,
                                                  const half_t* __restrict__ kk16,
                                                  const half_t* __restrict__ vv16) {
    __shared__ half_t sK[64][200];      // [key][hi96|lo96], pad 200
    __shared__ half_t sVT[192][72];     // [(plane*96+dim)][key64], pad 72
    __shared__ float  sP[4][16][68];    // per-wave P [qrow][key], pad 68
    const int tid = threadIdx.x;
    const int w = tid >> 6, l = tid & 63;
    const int lr = l & 15, lc = l >> 4;
    const size_t base = (size_t)blockIdx.x * 49152;
    const float ssc = 0.10206207261596575f / 256.0f;   // 1/sqrt(96) / (16*16)

    for (int pass = 0; pass < 2; ++pass) {
        f32x4 O[2][6];
        float mrow[2][4], lrow[2][4];
        #pragma unroll
        for (int qs = 0; qs < 2; ++qs) {
            #pragma unroll
            for (int dn = 0; dn < 6; ++dn) O[qs][dn] = (f32x4){0.f, 0.f, 0.f, 0.f};
            #pragma unroll
            for (int r = 0; r < 4; ++r) { mrow[qs][r] = -3e38f; lrow[qs][r] = 0.f; }
        }
        for (int kt = 0; kt < 4; ++kt) {
            __syncthreads();                                   // slabs free to overwrite
            #pragma unroll
            for (int c = 0; c < 6; ++c) {                      // stage K tile
                int ch = w + c * 4;
                *(f16x8*)&sK[l][ch * 8] =
                    *(const f16x8*)(kk16 + base + (size_t)(kt * 64 + l) * 192 + ch * 8);
            }
            #pragma unroll
            for (int c = 0; c < 6; ++c) {                      // stage V with LDS transpose
                int ch = w + c * 4;
                f16x8 vv = *(const f16x8*)(vv16 + base + (size_t)(kt * 64 + l) * 192 + ch * 8);
                #pragma unroll
                for (int j = 0; j < 8; ++j) sVT[ch * 8 + j][l] = vv[j];
            }
            __syncthreads();
            #pragma unroll
            for (int qs = 0; qs < 2; ++qs) {
                const int qrow0 = (pass * 2 + qs) * 64 + w * 16;
                f16x8 qf0[3], qf1[3];
                #pragma unroll
                for (int s = 0; s < 3; ++s) {
                    qf0[s] = *(const f16x8*)(qc + base + (size_t)(qrow0 + lr) * 192 + s * 32 + lc * 8);
                    qf1[s] = *(const f16x8*)(qc + base + (size_t)(qrow0 + lr) * 192 + 96 + s * 32 + lc * 8);
                }
                // ---- S = Q K^T (split-fp16: qh*kh + qh*kl + ql*kh) ----
                f32x4 sacc[4];
                #pragma unroll
                for (int nt = 0; nt < 4; ++nt) sacc[nt] = (f32x4){0.f, 0.f, 0.f, 0.f};
                #pragma unroll
                for (int s = 0; s < 3; ++s)
                    #pragma unroll
                    for (int nt = 0; nt < 4; ++nt) {
                        f16x8 kh = *(const f16x8*)&sK[nt * 16 + lr][s * 32 + lc * 8];
                        f16x8 klo = *(const f16x8*)&sK[nt * 16 + lr][96 + s * 32 + lc * 8];
                        sacc[nt] = __builtin_amdgcn_mfma_f32_16x16x32_f16(qf0[s], kh, sacc[nt], 0, 0, 0);
                        sacc[nt] = __builtin_amdgcn_mfma_f32_16x16x32_f16(qf0[s], klo, sacc[nt], 0, 0, 0);
                        sacc[nt] = __builtin_amdgcn_mfma_f32_16x16x32_f16(qf1[s], kh, sacc[nt], 0, 0, 0);
                    }
                // ---- scale + mask + online softmax (C-layout: row=lc*4+r, col=lr) ----
                float sv[4][4], mx[4] = {-3e38f, -3e38f, -3e38f, -3e38f};
                #pragma unroll
                for (int nt = 0; nt < 4; ++nt) {
                    int key = kt * 64 + nt * 16 + lr;
                    #pragma unroll
                    for (int r = 0; r < 4; ++r) {
                        float s_ = sacc[nt][r] * ssc;
                        if (key >= 255) s_ = -3e38f;
                        sv[nt][r] = s_;
                        mx[r] = fmaxf(mx[r], s_);
                    }
                }
                #pragma unroll
                for (int r = 0; r < 4; ++r) {
                    mx[r] = fmaxf(mx[r], __shfl_xor(mx[r], 1));
                    mx[r] = fmaxf(mx[r], __shfl_xor(mx[r], 2));
                    mx[r] = fmaxf(mx[r], __shfl_xor(mx[r], 4));
                    mx[r] = fmaxf(mx[r], __shfl_xor(mx[r], 8));
                }
                float alpha[4], rsum[4];
                #pragma unroll
                for (int r = 0; r < 4; ++r) {
                    float mn = fmaxf(mrow[qs][r], mx[r]);
                    alpha[r] = __expf(mrow[qs][r] - mn);
                    mrow[qs][r] = mn;
                    rsum[r] = 0.f;
                }
                float pv[4][4];
                #pragma unroll
                for (int nt = 0; nt < 4; ++nt)
                    #pragma unroll
                    for (int r = 0; r < 4; ++r) {
                        float p = __expf(sv[nt][r] - mrow[qs][r]);
                        pv[nt][r] = p;
                        rsum[r] += p;
                    }
                #pragma unroll
                for (int r = 0; r < 4; ++r) {
                    rsum[r] += __shfl_xor(rsum[r], 1);
                    rsum[r] += __shfl_xor(rsum[r], 2);
                    rsum[r] += __shfl_xor(rsum[r], 4);
                    rsum[r] += __shfl_xor(rsum[r], 8);
                    lrow[qs][r] = lrow[qs][r] * alpha[r] + rsum[r];
                }
                #pragma unroll
                for (int dn = 0; dn < 6; ++dn)
                    #pragma unroll
                    for (int r = 0; r < 4; ++r) O[qs][dn][r] *= alpha[r];
                // ---- P via LDS (wave-private), then O += P V ----
                #pragma unroll
                for (int nt = 0; nt < 4; ++nt)
                    #pragma unroll
                    for (int r = 0; r < 4; ++r)
                        sP[w][lc * 4 + r][nt * 16 + lr] = pv[nt][r];
                #pragma unroll
                for (int ks = 0; ks < 2; ++ks) {
                    const float* pp = &sP[w][lr][ks * 32 + lc * 8];
                    f16x8 ph, pl;
                    #pragma unroll
                    for (int j = 0; j < 8; ++j) {
                        float p = pp[j];
                        half_t h_ = (half_t)p;
                        ph[j] = h_;
                        pl[j] = (half_t)(p - (float)h_);
                    }
                    #pragma unroll
                    for (int dn = 0; dn < 6; ++dn) {
                        f16x8 vh = *(const f16x8*)&sVT[dn * 16 + lr][ks * 32 + lc * 8];
                        f16x8 vl = *(const f16x8*)&sVT[96 + dn * 16 + lr][ks * 32 + lc * 8];
                        O[qs][dn] = __builtin_amdgcn_mfma_f32_16x16x32_f16(ph, vh, O[qs][dn], 0, 0, 0);
                        O[qs][dn] = __builtin_amdgcn_mfma_f32_16x16x32_f16(ph, vl, O[qs][dn], 0, 0, 0);
                        O[qs][dn] = __builtin_amdgcn_mfma_f32_16x16x32_f16(pl, vh, O[qs][dn], 0, 0, 0);
                    }
                }
            }
        }
        // ---- epilogue: ctx(x16) = O / l, fp16 hi/lo in-place over q ----
        #pragma unroll
        for (int qs = 0; qs < 2; ++qs) {
            const int qrow0 = (pass * 2 + qs) * 64 + w * 16;
            #pragma unroll
            for (int r = 0; r < 4; ++r) {
                int qrow = qrow0 + lc * 4 + r;
                if (qrow >= Wn) continue;
                float inv = 1.0f / lrow[qs][r];
                #pragma unroll
                for (int dn = 0; dn < 6; ++dn) {
                    float val = O[qs][dn][r] * inv;
                    half_t hi = (half_t)val;
                    half_t lo = (half_t)(val - (float)hi);
                    size_t o = base + (size_t)qrow * 192 + dn * 16 + lr;
                    qc[o] = hi;
                    qc[o + 96] = lo;
                }
            }
        }
    }
}

// ---------------- row LayerNorm (optional fused fp16-pair split output) -----

template<int SPLIT>
__global__ __launch_bounds__(256) void k_ln(const float* __restrict__ X, const float* __restrict__ g,
                                            const float* __restrict__ bt, float* __restrict__ Y,
                                            half_t* __restrict__ Y16) {
    const int r = blockIdx.x, tid = threadIdx.x;
    __shared__ float red[256];
    const float* x = X + (size_t)r * Dd;
    float x0 = x[tid], x1 = x[tid + 256], x2 = x[tid + 512];
    red[tid] = x0 + x1 + x2; __syncthreads();
    for (int s = 128; s > 0; s >>= 1) { if (tid < s) red[tid] += red[tid + s]; __syncthreads(); }
    float mean = red[0] * (1.0f / 768.0f);
    __syncthreads();
    float d0 = x0 - mean, d1 = x1 - mean, d2 = x2 - mean;
    red[tid] = d0 * d0 + d1 * d1 + d2 * d2; __syncthreads();
    for (int s = 128; s > 0; s >>= 1) { if (tid < s) red[tid] += red[tid + s]; __syncthreads(); }
    float rs = rsqrtf(red[0] * (1.0f / 768.0f) + 1e-5f);
    float* y = Y + (size_t)r * Dd;
    float y0 = d0 * rs * g[tid]       + bt[tid];
    float y1 = d1 * rs * g[tid + 256] + bt[tid + 256];
    float y2 = d2 * rs * g[tid + 512] + bt[tid + 512];
    y[tid] = y0; y[tid + 256] = y1; y[tid + 512] = y2;
    if (SPLIT) {
        half_t* h = Y16 + (size_t)r * 1536;
        float t0 = y0 * 16.f, t1 = y1 * 16.f, t2 = y2 * 16.f;
        half_t h0 = (half_t)t0, h1 = (half_t)t1, h2 = (half_t)t2;
        h[tid] = h0; h[tid + 256] = h1; h[tid + 512] = h2;
        h[768 + tid] = (half_t)(t0 - (float)h0);
        h[768 + tid + 256] = (half_t)(t1 - (float)h1);
        h[768 + tid + 512] = (half_t)(t2 - (float)h2);
    }
}

// ---------------- final LN + 2-class linear + softmax + argmax --------------

__global__ __launch_bounds__(256) void k_final(const float* __restrict__ X, const float* __restrict__ g,
                                               const float* __restrict__ bt, const float* __restrict__ lw,
                                               const float* __restrict__ lb, float* __restrict__ out) {
    const int r = blockIdx.x, tid = threadIdx.x;
    __shared__ float red[256];
    const float* x = X + (size_t)r * Dd;
    float x0 = x[tid], x1 = x[tid + 256], x2 = x[tid + 512];
    red[tid] = x0 + x1 + x2; __syncthreads();
    for (int s = 128; s > 0; s >>= 1) { if (tid < s) red[tid] += red[tid + s]; __syncthreads(); }
    float mean = red[0] * (1.0f / 768.0f);
    __syncthreads();
    float d0 = x0 - mean, d1 = x1 - mean, d2 = x2 - mean;
    red[tid] = d0 * d0 + d1 * d1 + d2 * d2; __syncthreads();
    for (int s = 128; s > 0; s >>= 1) { if (tid < s) red[tid] += red[tid + s]; __syncthreads(); }
    float rs = rsqrtf(red[0] * (1.0f / 768.0f) + 1e-5f);
    __syncthreads();
    float n0 = d0 * rs * g[tid]       + bt[tid];
    float n1 = d1 * rs * g[tid + 256] + bt[tid + 256];
    float n2 = d2 * rs * g[tid + 512] + bt[tid + 512];
    float l0 = n0 * lw[2 * tid]     + n1 * lw[2 * (tid + 256)]     + n2 * lw[2 * (tid + 512)];
    float l1 = n0 * lw[2 * tid + 1] + n1 * lw[2 * (tid + 256) + 1] + n2 * lw[2 * (tid + 512) + 1];
    red[tid] = l0; __syncthreads();
    for (int s = 128; s > 0; s >>= 1) { if (tid < s) red[tid] += red[tid + s]; __syncthreads(); }
    l0 = red[0]; __syncthreads();
    red[tid] = l1; __syncthreads();
    for (int s = 128; s > 0; s >>= 1) { if (tid < s) red[tid] += red[tid + s]; __syncthreads(); }
    l1 = red[0];
    if (tid == 0) {
        l0 += lb[0]; l1 += lb[1];
        float m = fmaxf(l0, l1);
        float e0 = expf(l0 - m), e1 = expf(l1 - m);
        float inv = 1.0f / (e0 + e1);
        out[2 * r] = e0 * inv;
        out[2 * r + 1] = e1 * inv;
        out[2 * NROWS + r] = (l1 > l0) ? 1.0f : 0.0f;   // tie -> first index (0)
    }
}

// ---------------- launch --------------------------------------------------

extern "C" void kernel_launch(void* const* d_in, const int* in_sizes, int n_in,
                              void* d_out, int out_size, void* d_ws, size_t ws_size,
                              hipStream_t stream) {
    const float* ob  = (const float*)d_in[0];
    const int*   wid = (const int*)d_in[1];
    const float* Wq  = (const float*)d_in[2];  const float* bq  = (const float*)d_in[3];
    const float* Wk  = (const float*)d_in[4];  const float* bk  = (const float*)d_in[5];
    const float* Wv  = (const float*)d_in[6];  const float* bv  = (const float*)d_in[7];
    const float* Wo  = (const float*)d_in[8];  const float* bo  = (const float*)d_in[9];
    const float* g1  = (const float*)d_in[10]; const float* b1  = (const float*)d_in[11];
    const float* W1f = (const float*)d_in[12]; const float* b1f = (const float*)d_in[13];
    const float* W2f = (const float*)d_in[14]; const float* b2f = (const float*)d_in[15];
    const float* g2  = (const float*)d_in[16]; const float* b2  = (const float*)d_in[17];
    const float* ng  = (const float*)d_in[18]; const float* nb  = (const float*)d_in[19];
    const float* lw  = (const float*)d_in[20]; const float* lb  = (const float*)d_in[21];
    float* out = (float*)d_out;

    char* ws = (char*)d_ws;
    const size_t MB = 1u << 20;
    const size_t SLOT = 48 * MB;               // 50,331,648 B; SLOTH = SLOT/2 halves
    int* fi = (int*)ws;                        // 65,280 B
    float* bcat = (float*)(ws + 262144);       // 2304 floats
    char* S1 = ws + MB;
    char* S2 = S1 + SLOT;
    char* S3 = S2 + SLOT;
    char* S4 = S3 + SLOT;                      // total 193 MiB (proven OK)

    half_t* feat16 = (half_t*)S1;              // interleaved hi|lo, row = 1536 halves
    half_t* q16    = (half_t*)S2;              // [bh][256][192] -> ctx16 in-place
    half_t* k16    = (half_t*)S3;              // [bh][256][192]  (= q16 + SLOTH)
    half_t* v16    = (half_t*)S4;              // [bh][256][192]  (= q16 + 2*SLOTH)
    float*  t1     = (float*)S3;               // Wo out (k16 consumed)
    float*  xbuf   = (float*)S4;               // LN1 out (v16 consumed)
    half_t* x16    = (half_t*)S2;              // LN1 split out (ctx consumed by Wo)
    half_t* ffh_h  = (half_t*)S1;              // per-chunk hidden hi (feat16 consumed)
    half_t* ffh_l  = (half_t*)S3;              // per-chunk hidden lo (t1 consumed)
    float*  t2     = (float*)S2;               // overlays consumed x16 rows (3072 B stride)
    float*  x2     = (float*)S4;               // LN2 out (xbuf consumed)

    // weight prep: QKV hi contiguous [0,1769472), QKV lo [1769472,3538944)
    k_wsplit<<<dim3(24, 24), dim3(32, 8), 0, stream>>>(Wq, 768, 768, 0, 1769472);
    k_wsplit<<<dim3(24, 24), dim3(32, 8), 0, stream>>>(Wk, 768, 768, 589824, 2359296);
    k_wsplit<<<dim3(24, 24), dim3(32, 8), 0, stream>>>(Wv, 768, 768, 1179648, 2949120);
    k_wsplit<<<dim3(24, 24), dim3(32, 8), 0, stream>>>(Wo, 768, 768, OFF_WO_H, OFF_WO_L);
    k_wsplit<<<dim3(96, 24), dim3(32, 8), 0, stream>>>(W1f, 768, 3072, OFF_W1_H, OFF_W1_L);
    k_wsplit<<<dim3(24, 96), dim3(32, 8), 0, stream>>>(W2f, 3072, 768, OFF_W2_H, OFF_W2_L);
    k_bcat<<<9, 256, 0, stream>>>(bq, bk, bv, bcat);

    k_init_fi<<<(Bsz * Wn + 255) / 256, 256, 0, stream>>>(fi);
    k_scan<<<(Bsz * Tt) / 256, 256, 0, stream>>>(wid, fi);
    k_gather<<<(NROWS * 192 + 255) / 256, 256, 0, stream>>>((const float4*)ob, fi, feat16);

    // fused QKV GEMM -> q16 / k16 / v16 (2304 blocks = 9/CU, XCD-swizzled)
    k_gemm16<5, 0, 128><<<dim3(18, 128), 256, 0, stream>>>(
        feat16, feat16 + 768, 1536, OFF_QKV_H, OFF_QKV_L,
        bcat, nullptr, q16, nullptr, NROWS, 2304, Dd);

    k_attn2<<<Bsz * Hh, 256, 0, stream>>>(q16, k16, v16);     // ctx overwrites q16

    // t1 = feat + ctx@Wo + bo (AMODE 1 gathers head-major ctx) ; x = LN1(t1)
    k_gemm16<1, 1, 128><<<dim3(6, 128), 256, 0, stream>>>(
        q16, q16 + 96, 0, OFF_WO_H, OFF_WO_L,
        bo, feat16, t1, nullptr, NROWS, Dd, Dd);
    k_ln<1><<<NROWS, 256, 0, stream>>>(t1, g1, b1, xbuf, x16);

    // FFN in 2 row-chunks of 8160; FFN2 uses 64-wide N tiles (768 blocks = 3/CU)
    for (int c = 0; c < 2; ++c) {
        const int r0 = c * 8160, mc = 8160;
        k_gemm16<2, 0, 128><<<dim3(24, 64), 256, 0, stream>>>(
            x16 + (size_t)r0 * 1536, x16 + (size_t)r0 * 1536 + 768, 1536,
            OFF_W1_H, OFF_W1_L, b1f, nullptr, ffh_h, ffh_l, mc, 3072, Dd);
        k_gemm16<3, 0, 64><<<dim3(12, 64), 256, 0, stream>>>(
            ffh_h, ffh_l, 3072, OFF_W2_H, OFF_W2_L, b2f, xbuf + (size_t)r0 * Dd,
            t2 + (size_t)r0 * Dd, nullptr, mc, Dd, 3072);
    }

    k_ln<0><<<NROWS, 256, 0, stream>>>(t2, g2, b2, x2, nullptr);
    k_final<<<NROWS, 256, 0, stream>>>(x2, ng, nb, lw, lb, out);
}